// Round 16
// baseline (252.666 us; speedup 1.0000x reference)
//
#include <hip/hip_runtime.h>

// Problem dims
#define NT 8192      // N*H*W tokens
#define DM 256
#define HH 64
#define WW 64

typedef unsigned short u16;
typedef __attribute__((ext_vector_type(8))) short short8;  // 8 x bf16 mfma frag
typedef __attribute__((ext_vector_type(4))) float f4;

__device__ __forceinline__ float bf2f(u16 u){
  union { unsigned int i; float f; } v; v.i = ((unsigned int)u) << 16; return v.f;
}
__device__ __forceinline__ u16 f2bf(float f){
  union { float f; unsigned int i; } v; v.f = f;
  unsigned int r = (v.i + 0x7fffu + ((v.i >> 16) & 1u)) >> 16;
  return (u16)r;
}
// async global->LDS 16B (direct DMA, no VGPR round trip)
__device__ __forceinline__ void gld16(const void* g, void* l){
  __builtin_amdgcn_global_load_lds(
      (const __attribute__((address_space(1))) unsigned int*)g,
      (__attribute__((address_space(3))) unsigned int*)l, 16, 0, 0);
}

// ---------------------------------------------------------------------------
// ALL prep in ONE dispatch (1794 blocks) — r13, proven clean:
//  b < 1024: prolog path — per 8 tokens: offsets GEMV + hs->hi/lo + emb->hi
//  1024..1279: qkvo transposes; 1280..1535: W1^T; 1536..1791: W2^T;
//  1792/1793: fold W_kvp/b_kvp through Wk/Wv -> kvc.
// ---------------------------------------------------------------------------
__global__ __launch_bounds__(256) void prepall_k(const float* __restrict__ hs,
                                                 const float* __restrict__ emb,
                                                 const float* __restrict__ Woff,
                                                 const float* __restrict__ boff,
                                                 const float* __restrict__ Wq,
                                                 const float* __restrict__ Wk,
                                                 const float* __restrict__ Wv,
                                                 const float* __restrict__ Wo,
                                                 const float* __restrict__ W1,
                                                 const float* __restrict__ W2,
                                                 const float* __restrict__ Wkvp,
                                                 const float* __restrict__ bkvp,
                                                 const float* __restrict__ bk,
                                                 const float* __restrict__ bv,
                                                 u16* __restrict__ hsph,
                                                 u16* __restrict__ hspl,
                                                 u16* __restrict__ embh,
                                                 float* __restrict__ off,
                                                 float* __restrict__ loc,
                                                 u16* __restrict__ qkvoTh,
                                                 u16* __restrict__ qkvoTl,
                                                 u16* __restrict__ W1Th,
                                                 u16* __restrict__ W1Tl,
                                                 u16* __restrict__ W2Th,
                                                 u16* __restrict__ W2Tl,
                                                 float* __restrict__ kvc){
  __shared__ float smem[10240];
  const int blk = blockIdx.x;
  const int tid = threadIdx.x;
  if (blk < 1024){
    // ---- prolog path ----
    float* hsl = smem;          // [2048]
    float* wl  = smem + 2048;   // [8192]
    const int t0 = blk * 8;
    for (int i = tid; i < 8192; i += 256) wl[i] = Woff[i];
    for (int i = tid; i < 2048; i += 256) hsl[i] = hs[(size_t)t0 * 256 + i];
    __syncthreads();
    {
      const int g = tid >> 5, o = tid & 31;
      float acc = 0.f;
      #pragma unroll 8
      for (int d = 0; d < 256; d++) acc += hsl[g * 256 + d] * wl[d * 32 + o];
      acc += boff[o];
      float sg = 1.f / (1.f + expf(-acc));
      float of = 60.f * sg - 30.f;
      int tok = t0 + g;
      int hh = (tok >> 6) & 63, ww = tok & 63;
      float base = (o & 1) ? (float)ww : (float)hh;
      float l = fminf(fmaxf(base + of, 0.f), 63.f);
      off[tok * 32 + o] = of;
      loc[tok * 32 + o] = l;
    }
    for (int c = tid; c < 512; c += 256){
      f4 v = *(const f4*)&hsl[c * 4];
      ushort4 h, l;
      h.x = f2bf(v.x); l.x = f2bf(v.x - bf2f(h.x));
      h.y = f2bf(v.y); l.y = f2bf(v.y - bf2f(h.y));
      h.z = f2bf(v.z); l.z = f2bf(v.z - bf2f(h.z));
      h.w = f2bf(v.w); l.w = f2bf(v.w - bf2f(h.w));
      ((ushort4*)hsph)[(size_t)t0 * 64 + c] = h;
      ((ushort4*)hspl)[(size_t)t0 * 64 + c] = l;
      f4 e = ((const f4*)emb)[(size_t)t0 * 64 + c];
      ushort4 eh;
      eh.x = f2bf(e.x); eh.y = f2bf(e.y); eh.z = f2bf(e.z); eh.w = f2bf(e.w);
      ((ushort4*)embh)[(size_t)t0 * 64 + c] = eh;
    }
    return;
  }
  const int b = blk - 1024;
  if (b >= 768){               // prepkv fold
    const float* Wx = (b == 768) ? Wk : Wv;
    const float* bx = (b == 768) ? bk : bv;
    float* o = kvc + (b - 768) * 768;
    int e = tid;
    float a0 = 0.f, a1 = 0.f, ab = 0.f;
    for (int d = 0; d < 256; d++){
      float w = Wx[d * 256 + e];
      a0 += Wkvp[d] * w;
      a1 += Wkvp[256 + d] * w;
      ab += bkvp[d] * w;
    }
    o[e] = a0; o[256 + e] = a1; o[512 + e] = ab + bx[e];
    return;
  }
  // ---- weight transpose path ----
  float (*t)[33] = (float(*)[33])smem;
  const float* src; u16 *dh, *dl; int R, C, c0, r0;
  if (b < 256){
    int mat = b >> 6, tt = b & 63;
    src = mat == 0 ? Wq : mat == 1 ? Wk : mat == 2 ? Wv : Wo;
    dh = qkvoTh + mat * 65536; dl = qkvoTl + mat * 65536;
    R = 256; C = 256; c0 = (tt & 7) * 32; r0 = (tt >> 3) * 32;
  } else if (b < 512){
    int tt = b - 256; src = W1; dh = W1Th; dl = W1Tl; R = 256; C = 1024;
    c0 = (tt & 31) * 32; r0 = (tt >> 5) * 32;
  } else {
    int tt = b - 512; src = W2; dh = W2Th; dl = W2Tl; R = 1024; C = 256;
    c0 = (tt & 7) * 32; r0 = (tt >> 3) * 32;
  }
  int tx = tid & 31, ty = tid >> 5;
  for (int i = ty; i < 32; i += 8) t[i][tx] = src[(size_t)(r0 + i) * C + c0 + tx];
  __syncthreads();
  for (int i = ty; i < 32; i += 8){
    float x = t[tx][i];
    u16 h = f2bf(x);
    size_t idx = (size_t)(c0 + i) * R + r0 + tx;
    dh[idx] = h;
    dl[idx] = f2bf(x - bf2f(h));
  }
}

// ---------------------------------------------------------------------------
// Grouped q + EKV GEMM, ONE dispatch (1536 blocks), BM=BN=64, BK=64, K=256.
// r13-proven per-BK staging (32 KB LDS, 5 blocks/CU).
//  blocks 0..511:    q   = hs(hi/lo, 3-pass) x WqT(hi/lo) + bq -> fp32 qb
//  blocks 512..1535: EKV = emb(hi, 2-pass)  x kvWT(hi/lo)      -> packed bf16
// ---------------------------------------------------------------------------
__global__ __launch_bounds__(256) void qekv_k(const u16* __restrict__ hsph,
                                              const u16* __restrict__ hspl,
                                              const u16* __restrict__ WqTh,
                                              const u16* __restrict__ WqTl,
                                              const float* __restrict__ bq,
                                              const u16* __restrict__ embh,
                                              const u16* __restrict__ kvWh,
                                              const u16* __restrict__ kvWl,
                                              float* __restrict__ qb,
                                              u16* __restrict__ EKV){
  __shared__ __align__(16) u16 Ah[8][64][8];
  __shared__ __align__(16) u16 Al[8][64][8];
  __shared__ __align__(16) u16 Bh[8][64][8];
  __shared__ __align__(16) u16 Bl[8][64][8];
  const int bid = blockIdx.x;
  const bool isQ = bid < 512;
  const int b2 = isQ ? bid : bid - 512;
  const int m0 = (b2 & 127) << 6;
  const int n0 = (b2 >> 7) << 6;
  const int K = 256;
  const u16* Agh = isQ ? hsph : embh;
  const u16* Bgh = isQ ? WqTh : kvWh;
  const u16* Bgl = isQ ? WqTl : kvWl;
  const int tid = threadIdx.x;
  const int lane = tid & 63, wave = tid >> 6;
  const int quad = lane >> 4, l15 = lane & 15;
  const int wm = (wave >> 1) << 5, wn = (wave & 1) << 5;
  const int ar = tid & 63, aq = tid >> 6;
  const u16* gAh = Agh + (size_t)(m0 + ar) * K + aq * 8;
  const u16* gAl = hspl + (size_t)(m0 + ar) * K + aq * 8;   // only read if isQ
  const u16* gBh = Bgh + (size_t)(n0 + ar) * K + aq * 8;
  const u16* gBl = Bgl + (size_t)(n0 + ar) * K + aq * 8;
  f4 acc[2][2] = {};
  for (int k0 = 0; k0 < K; k0 += 64){
    __syncthreads();
    gld16(gAh + k0,      &Ah[aq][ar][0]);
    gld16(gAh + k0 + 32, &Ah[aq + 4][ar][0]);
    if (isQ){
      gld16(gAl + k0,      &Al[aq][ar][0]);
      gld16(gAl + k0 + 32, &Al[aq + 4][ar][0]);
    }
    gld16(gBh + k0,      &Bh[aq][ar][0]);
    gld16(gBh + k0 + 32, &Bh[aq + 4][ar][0]);
    gld16(gBl + k0,      &Bl[aq][ar][0]);
    gld16(gBl + k0 + 32, &Bl[aq + 4][ar][0]);
    asm volatile("s_waitcnt vmcnt(0)" ::: "memory");
    __syncthreads();
    #pragma unroll
    for (int kh = 0; kh < 2; kh++){
      const int q = kh * 4 + quad;
      short8 ahf[2], alf[2], bhf[2], blf[2];
      #pragma unroll
      for (int i = 0; i < 2; i++){
        ahf[i] = *(const short8*)(&Ah[q][wm + i * 16 + l15][0]);
        bhf[i] = *(const short8*)(&Bh[q][wn + i * 16 + l15][0]);
        blf[i] = *(const short8*)(&Bl[q][wn + i * 16 + l15][0]);
      }
      if (isQ){
        #pragma unroll
        for (int i = 0; i < 2; i++)
          alf[i] = *(const short8*)(&Al[q][wm + i * 16 + l15][0]);
      }
      #pragma unroll
      for (int mi = 0; mi < 2; mi++)
      #pragma unroll
      for (int ni = 0; ni < 2; ni++){
        if (isQ)
          acc[mi][ni] = __builtin_amdgcn_mfma_f32_16x16x32_bf16(alf[mi], bhf[ni], acc[mi][ni], 0, 0, 0);
        acc[mi][ni] = __builtin_amdgcn_mfma_f32_16x16x32_bf16(ahf[mi], blf[ni], acc[mi][ni], 0, 0, 0);
        acc[mi][ni] = __builtin_amdgcn_mfma_f32_16x16x32_bf16(ahf[mi], bhf[ni], acc[mi][ni], 0, 0, 0);
      }
    }
  }
  #pragma unroll
  for (int mi = 0; mi < 2; mi++)
  #pragma unroll
  for (int ni = 0; ni < 2; ni++){
    int col = n0 + wn + ni * 16 + l15;
    int rowb = m0 + wm + mi * 16 + quad * 4;
    if (isQ){
      float bval = bq[col];
      #pragma unroll
      for (int rg = 0; rg < 4; rg++)
        qb[(size_t)(rowb + rg) * 256 + col] = acc[mi][ni][rg] + bval;
    } else {
      int part = col >> 8, d = col & 255;
      int pc = ((d >> 2) << 3) + (part << 2) + (d & 3);
      #pragma unroll
      for (int rg = 0; rg < 4; rg++)
        EKV[(size_t)(rowb + rg) * 512 + pc] = f2bf(acc[mi][ni][rg]);
    }
  }
}

// ---------------------------------------------------------------------------
// Split-precision MFMA GEMM (r13 template) — O-proj (K=256) + W2 (K=1024).
// APREC/BPREC: 2 = hi/lo planes, 1 = hi only.
// EPI 0: fp32 +bias -> C0.   EPI 1: gelu(tanh) -> bf16 plane C0.
// ---------------------------------------------------------------------------
template<int BN, int APREC, int BPREC, int EPI>
__global__ __launch_bounds__(256) void gemm_k(const u16* __restrict__ Agh,
                                              const u16* __restrict__ Agl,
                                              const u16* __restrict__ Bgh,
                                              const u16* __restrict__ Bgl,
                                              const float* __restrict__ bias,
                                              void* __restrict__ C0,
                                              int M, int N, int K){
  constexpr int NF = BN / 32;
  __shared__ __align__(16) u16 Ah[8][64][8];
  __shared__ __align__(16) u16 Al[APREC == 2 ? 8 : 1][64][8];
  __shared__ __align__(16) u16 Bh[8][BN][8];
  __shared__ __align__(16) u16 Bl[BPREC == 2 ? 8 : 1][BN][8];
  const int m0 = blockIdx.x << 6, n0 = blockIdx.y * BN;
  const int tid = threadIdx.x;
  const int lane = tid & 63, wave = tid >> 6;
  const int quad = lane >> 4, l15 = lane & 15;
  const int wm = (wave >> 1) << 5;
  const int wn = (wave & 1) * (BN >> 1);
  const int ar = tid & 63, aq = tid >> 6;
  const u16* gAh = Agh + (size_t)(m0 + ar) * K + aq * 8;
  const u16* gAl = (APREC == 2) ? (Agl + (size_t)(m0 + ar) * K + aq * 8) : nullptr;
  const int br = (BN == 128) ? (tid & 127) : (tid & 63);
  const int bq = (BN == 128) ? (tid >> 7) : (tid >> 6);
  const u16* gBh = Bgh + (size_t)(n0 + br) * K + bq * 8;
  const u16* gBl = (BPREC == 2) ? (Bgl + (size_t)(n0 + br) * K + bq * 8) : nullptr;
  f4 acc[2][NF] = {};
  for (int k0 = 0; k0 < K; k0 += 64){
    __syncthreads();
    gld16(gAh + k0,      &Ah[aq][ar][0]);
    gld16(gAh + k0 + 32, &Ah[aq + 4][ar][0]);
    if (APREC == 2){
      gld16(gAl + k0,      &Al[aq][ar][0]);
      gld16(gAl + k0 + 32, &Al[aq + 4][ar][0]);
    }
    gld16(gBh + k0,      &Bh[bq][br][0]);
    gld16(gBh + k0 + 32, &Bh[bq + 4][br][0]);
    if (BPREC == 2){
      gld16(gBl + k0,      &Bl[bq][br][0]);
      gld16(gBl + k0 + 32, &Bl[bq + 4][br][0]);
    }
    asm volatile("s_waitcnt vmcnt(0)" ::: "memory");
    __syncthreads();
    #pragma unroll
    for (int kh = 0; kh < 2; kh++){
      const int q = kh * 4 + quad;
      short8 ahf[2], alf[2], bhf[NF], blf[NF];
      #pragma unroll
      for (int i = 0; i < 2; i++){
        ahf[i] = *(const short8*)(&Ah[q][wm + i * 16 + l15][0]);
        if (APREC == 2) alf[i] = *(const short8*)(&Al[q][wm + i * 16 + l15][0]);
      }
      #pragma unroll
      for (int i = 0; i < NF; i++){
        bhf[i] = *(const short8*)(&Bh[q][wn + i * 16 + l15][0]);
        if (BPREC == 2) blf[i] = *(const short8*)(&Bl[q][wn + i * 16 + l15][0]);
      }
      #pragma unroll
      for (int mi = 0; mi < 2; mi++)
      #pragma unroll
      for (int ni = 0; ni < NF; ni++){
        if (APREC == 2)
          acc[mi][ni] = __builtin_amdgcn_mfma_f32_16x16x32_bf16(alf[mi], bhf[ni], acc[mi][ni], 0, 0, 0);
        if (BPREC == 2)
          acc[mi][ni] = __builtin_amdgcn_mfma_f32_16x16x32_bf16(ahf[mi], blf[ni], acc[mi][ni], 0, 0, 0);
        acc[mi][ni] = __builtin_amdgcn_mfma_f32_16x16x32_bf16(ahf[mi], bhf[ni], acc[mi][ni], 0, 0, 0);
      }
    }
  }
  #pragma unroll
  for (int mi = 0; mi < 2; mi++)
  #pragma unroll
  for (int ni = 0; ni < NF; ni++){
    int col = n0 + wn + ni * 16 + l15;
    float bval = bias ? bias[col] : 0.f;
    int rowb = m0 + wm + mi * 16 + quad * 4;
    #pragma unroll
    for (int rg = 0; rg < 4; rg++){
      float v = acc[mi][ni][rg] + bval;
      int row = rowb + rg;
      if (EPI == 0){
        ((float*)C0)[(size_t)row * N + col] = v;
      } else {
        float t = v + 0.044715f * v * v * v;
        float g = 0.5f * v * (1.f + tanhf(0.7978845608f * t));
        ((u16*)C0)[(size_t)row * N + col] = f2bf(g);
      }
    }
  }
}

// ---------------------------------------------------------------------------
// Dedicated W1 GEMM: 128x128 tile, BK=64, A bf16 plane, B hi plane (1-pass),
// gelu -> bf16. Proven clean (r10).
// ---------------------------------------------------------------------------
__global__ __launch_bounds__(256) void gemm128_k(const u16* __restrict__ Agh,
                                                 const u16* __restrict__ Bgh,
                                                 const float* __restrict__ bias,
                                                 u16* __restrict__ C0,
                                                 int M, int N, int K){
  __shared__ __align__(16) u16 Ah[8][128][8];
  __shared__ __align__(16) u16 Bh[8][128][8];
  const int m0 = blockIdx.x << 7, n0 = blockIdx.y << 7;
  const int tid = threadIdx.x;
  const int lane = tid & 63, wave = tid >> 6;
  const int quad = lane >> 4, l15 = lane & 15;
  const int wm = (wave >> 1) << 6, wn = (wave & 1) << 6;
  const int ar = tid & 127, q0 = tid >> 7;
  const u16* gA  = Agh + (size_t)(m0 + ar) * K + q0 * 8;
  const u16* gBhp = Bgh + (size_t)(n0 + ar) * K + q0 * 8;
  f4 acc[4][4] = {};
  for (int k0 = 0; k0 < K; k0 += 64){
    __syncthreads();
    #pragma unroll
    for (int j = 0; j < 4; j++){
      gld16(gA   + k0 + j * 16, &Ah[q0 + 2 * j][ar][0]);
      gld16(gBhp + k0 + j * 16, &Bh[q0 + 2 * j][ar][0]);
    }
    asm volatile("s_waitcnt vmcnt(0)" ::: "memory");
    __syncthreads();
    #pragma unroll
    for (int kh = 0; kh < 2; kh++){
      const int q = kh * 4 + quad;
      short8 af[4], bh8[4];
      #pragma unroll
      for (int i = 0; i < 4; i++){
        af[i]  = *(const short8*)(&Ah[q][wm + i * 16 + l15][0]);
        bh8[i] = *(const short8*)(&Bh[q][wn + i * 16 + l15][0]);
      }
      #pragma unroll
      for (int mi = 0; mi < 4; mi++)
      #pragma unroll
      for (int ni = 0; ni < 4; ni++)
        acc[mi][ni] = __builtin_amdgcn_mfma_f32_16x16x32_bf16(af[mi], bh8[ni], acc[mi][ni], 0, 0, 0);
    }
  }
  #pragma unroll
  for (int mi = 0; mi < 4; mi++)
  #pragma unroll
  for (int ni = 0; ni < 4; ni++){
    int col = n0 + wn + ni * 16 + l15;
    float bval = bias[col];
    int rowb = m0 + wm + mi * 16 + quad * 4;
    #pragma unroll
    for (int rg = 0; rg < 4; rg++){
      float v = acc[mi][ni][rg] + bval;
      float t = v + 0.044715f * v * v * v;
      float g = 0.5f * v * (1.f + tanhf(0.7978845608f * t));
      C0[(size_t)(rowb + rg) * N + col] = f2bf(g);
    }
  }
}

// ---------------------------------------------------------------------------
// Attention, DUAL-CHAIN online softmax: two independent online states over
// s=0..7 and s=8..15, merged at the end. Halves the serial chain depth and
// doubles per-iteration load ILP for only ~10 extra VGPRs (vs +64 for flat).
// One wave per token; lane owns dims [4*lane,4*lane+4).
// ---------------------------------------------------------------------------
__device__ __forceinline__ void unpack8(int4 p, f4& k4, f4& v4){
  k4.x = bf2f((u16)(p.x & 0xffff)); k4.y = bf2f((u16)((unsigned)p.x >> 16));
  k4.z = bf2f((u16)(p.y & 0xffff)); k4.w = bf2f((u16)((unsigned)p.y >> 16));
  v4.x = bf2f((u16)(p.z & 0xffff)); v4.y = bf2f((u16)((unsigned)p.z >> 16));
  v4.z = bf2f((u16)(p.w & 0xffff)); v4.w = bf2f((u16)((unsigned)p.w >> 16));
}

__device__ __forceinline__ void gatherKV(const int4* __restrict__ E, int base,
                                         int lane,
                                         const float* __restrict__ locb,
                                         const float* __restrict__ offb,
                                         int tok, int s,
                                         f4 wk0, f4 wk1, f4 bkv,
                                         f4 wv0, f4 wv1, f4 bvv,
                                         f4& kk, f4& vv){
  float y = locb[tok * 32 + s * 2], x = locb[tok * 32 + s * 2 + 1];
  float o0 = offb[tok * 32 + s * 2], o1 = offb[tok * 32 + s * 2 + 1];
  float yf = floorf(y), xf = floorf(x);
  int y0 = (int)yf, x0 = (int)xf;
  int y1 = min(y0 + 1, 63), x1 = min(x0 + 1, 63);
  float wy = y - yf, wx = x - xf;
  int4 p00 = E[(size_t)(base + y0 * 64 + x0) * 64 + lane];
  int4 p01 = E[(size_t)(base + y0 * 64 + x1) * 64 + lane];
  int4 p10 = E[(size_t)(base + y1 * 64 + x0) * 64 + lane];
  int4 p11 = E[(size_t)(base + y1 * 64 + x1) * 64 + lane];
  f4 k00, v00, k01, v01, k10, v10, k11, v11;
  unpack8(p00, k00, v00); unpack8(p01, k01, v01);
  unpack8(p10, k10, v10); unpack8(p11, k11, v11);
  float w00 = (1.f - wy) * (1.f - wx), w01 = (1.f - wy) * wx;
  float w10 = wy * (1.f - wx), w11 = wy * wx;
  kk = w00 * k00 + w01 * k01 + w10 * k10 + w11 * k11;
  vv = w00 * v00 + w01 * v01 + w10 * v10 + w11 * v11;
  kk += o0 * wk0 + o1 * wk1 + bkv;
  vv += o0 * wv0 + o1 * wv1 + bvv;
}

__global__ __launch_bounds__(256) void attn_k(const float* __restrict__ q,
                                              const u16* __restrict__ EKV,
                                              const float* __restrict__ offb,
                                              const float* __restrict__ locb,
                                              const float* __restrict__ kvc,
                                              u16* __restrict__ ah){
  const int tid = threadIdx.x;
  const int wave = tid >> 6, lane = tid & 63;
  const int tok = blockIdx.x * 4 + wave;
  const int base = (tok >> 12) << 12;   // n*4096
  const int4* E = (const int4*)EKV;     // 16B per (row,lane)
  const f4* kvc4 = (const f4*)kvc;
  f4 qv  = *((const f4*)q + (size_t)tok * 64 + lane);
  f4 wk0 = kvc4[lane], wk1 = kvc4[64 + lane], bkv = kvc4[128 + lane];
  f4 wv0 = kvc4[192 + lane], wv1 = kvc4[256 + lane], bvv = kvc4[320 + lane];
  float m1 = -1e30f, l1 = 0.f, m2 = -1e30f, l2 = 0.f;
  f4 ac1 = {0.f, 0.f, 0.f, 0.f}, ac2 = {0.f, 0.f, 0.f, 0.f};
  #pragma unroll
  for (int s = 0; s < 8; s++){
    f4 kk1, vv1, kk2, vv2;
    gatherKV(E, base, lane, locb, offb, tok, s,     wk0, wk1, bkv, wv0, wv1, bvv, kk1, vv1);
    gatherKV(E, base, lane, locb, offb, tok, s + 8, wk0, wk1, bkv, wv0, wv1, bvv, kk2, vv2);
    float p1 = qv.x * kk1.x + qv.y * kk1.y + qv.z * kk1.z + qv.w * kk1.w;
    float p2 = qv.x * kk2.x + qv.y * kk2.y + qv.z * kk2.z + qv.w * kk2.w;
    p1 += __shfl_xor(p1, 1); p1 += __shfl_xor(p1, 2);
    p1 += __shfl_xor(p1, 4); p1 += __shfl_xor(p1, 8);
    p2 += __shfl_xor(p2, 1); p2 += __shfl_xor(p2, 2);
    p2 += __shfl_xor(p2, 4); p2 += __shfl_xor(p2, 8);
    p1 *= 0.125f; p2 *= 0.125f;   // /sqrt(64)
    float mn1 = fmaxf(m1, p1);
    float c1 = __expf(m1 - mn1), w1 = __expf(p1 - mn1);
    l1 = l1 * c1 + w1;
    ac1 = ac1 * c1 + w1 * vv1;
    m1 = mn1;
    float mn2 = fmaxf(m2, p2);
    float c2 = __expf(m2 - mn2), w2 = __expf(p2 - mn2);
    l2 = l2 * c2 + w2;
    ac2 = ac2 * c2 + w2 * vv2;
    m2 = mn2;
  }
  // merge the two online states
  float M = fmaxf(m1, m2);
  float e1 = __expf(m1 - M), e2 = __expf(m2 - M);
  float L = l1 * e1 + l2 * e2;
  f4 acc = ac1 * e1 + ac2 * e2;
  acc *= (1.f / L);
  ushort4 h;
  h.x = f2bf(acc.x); h.y = f2bf(acc.y); h.z = f2bf(acc.z); h.w = f2bf(acc.w);
  *(ushort4*)(ah + (size_t)tok * 256 + lane * 4) = h;
}

// ---------------------------------------------------------------------------
// LayerNorm(a + b) * scale + bias. One wave per token.
// INP: 0 -> a0 fp32; 1 -> a0/a1 hi/lo planes.  OUTP: 0 -> fp32; 1 -> planes.
// ---------------------------------------------------------------------------
template<int INP, int OUTP>
__global__ __launch_bounds__(256) void ln_k(const void* __restrict__ a0,
                                            const void* __restrict__ a1,
                                            const float* __restrict__ b,
                                            const float* __restrict__ sc,
                                            const float* __restrict__ bi,
                                            void* __restrict__ o0,
                                            void* __restrict__ o1){
  const int tid = threadIdx.x;
  const int wave = tid >> 6, lane = tid & 63;
  const int tok = blockIdx.x * 4 + wave;
  float x0, x1, x2, x3;
  if (INP){
    ushort4 h = ((const ushort4*)a0)[(size_t)tok * 64 + lane];
    ushort4 lo = ((const ushort4*)a1)[(size_t)tok * 64 + lane];
    x0 = bf2f(h.x) + bf2f(lo.x); x1 = bf2f(h.y) + bf2f(lo.y);
    x2 = bf2f(h.z) + bf2f(lo.z); x3 = bf2f(h.w) + bf2f(lo.w);
  } else {
    f4 av = ((const f4*)a0)[(size_t)tok * 64 + lane];
    x0 = av.x; x1 = av.y; x2 = av.z; x3 = av.w;
  }
  f4 bv = ((const f4*)b)[(size_t)tok * 64 + lane];
  x0 += bv.x; x1 += bv.y; x2 += bv.z; x3 += bv.w;
  float sm = x0 + x1 + x2 + x3;
  float sq = x0 * x0 + x1 * x1 + x2 * x2 + x3 * x3;
  #pragma unroll
  for (int mm = 1; mm < 64; mm <<= 1){ sm += __shfl_xor(sm, mm); sq += __shfl_xor(sq, mm); }
  float mean = sm * (1.f / 256.f);
  float var = sq * (1.f / 256.f) - mean * mean;
  float rs = rsqrtf(var + 1e-6f);
  f4 sv = ((const f4*)sc)[lane];
  f4 bb = ((const f4*)bi)[lane];
  float y0 = (x0 - mean) * rs * sv.x + bb.x;
  float y1 = (x1 - mean) * rs * sv.y + bb.y;
  float y2 = (x2 - mean) * rs * sv.z + bb.z;
  float y3 = (x3 - mean) * rs * sv.w + bb.w;
  if (OUTP){
    ushort4 h, lo;
    h.x = f2bf(y0); lo.x = f2bf(y0 - bf2f(h.x));
    h.y = f2bf(y1); lo.y = f2bf(y1 - bf2f(h.y));
    h.z = f2bf(y2); lo.z = f2bf(y2 - bf2f(h.z));
    h.w = f2bf(y3); lo.w = f2bf(y3 - bf2f(h.w));
    ((ushort4*)o0)[(size_t)tok * 64 + lane] = h;
    ((ushort4*)o1)[(size_t)tok * 64 + lane] = lo;
  } else {
    f4 ov = {y0, y1, y2, y3};
    ((f4*)o0)[(size_t)tok * 64 + lane] = ov;
  }
}

// ---------------------------------------------------------------------------
extern "C" void kernel_launch(void* const* d_in, const int* in_sizes, int n_in,
                              void* d_out, int out_size, void* d_ws, size_t ws_size,
                              hipStream_t stream){
  const float* hs   = (const float*)d_in[0];
  const float* emb  = (const float*)d_in[1];
  const float* Woff = (const float*)d_in[2];
  const float* boff = (const float*)d_in[3];
  const float* Wkvp = (const float*)d_in[4];
  const float* bkvp = (const float*)d_in[5];
  const float* Wq   = (const float*)d_in[6];
  const float* bq   = (const float*)d_in[7];
  const float* Wk   = (const float*)d_in[8];
  const float* bk   = (const float*)d_in[9];
  const float* Wv   = (const float*)d_in[10];
  const float* bv   = (const float*)d_in[11];
  const float* Wo   = (const float*)d_in[12];
  const float* bo   = (const float*)d_in[13];
  const float* ln1s = (const float*)d_in[14];
  const float* ln1b = (const float*)d_in[15];
  const float* ln2s = (const float*)d_in[16];
  const float* ln2b = (const float*)d_in[17];
  const float* W1   = (const float*)d_in[18];
  const float* b1   = (const float*)d_in[19];
  const float* W2   = (const float*)d_in[20];
  const float* b2   = (const float*)d_in[21];

  char* w = (char*)d_ws;
  auto alloc = [&](size_t bytes){ char* p = w; w += (bytes + 255) & ~(size_t)255; return p; };
  // weight planes: [WqT | WkT | WvT | WoT] contiguous hi and lo
  u16* qkvoTh = (u16*)alloc(4 * 65536 * 2);
  u16* qkvoTl = (u16*)alloc(4 * 65536 * 2);
  u16* WqTh = qkvoTh;              u16* WqTl = qkvoTl;
  u16* kvWh = qkvoTh + 65536;      u16* kvWl = qkvoTl + 65536;   // [512,256]
  u16* WoTh = qkvoTh + 3 * 65536;
  u16* W1Th = (u16*)alloc(262144 * 2); u16* W1Tl = (u16*)alloc(262144 * 2);
  u16* W2Th = (u16*)alloc(262144 * 2); u16* W2Tl = (u16*)alloc(262144 * 2);
  float* kvc = (float*)alloc(1536 * 4);
  // slot1 (8.4 MB): hs hi/lo planes / attn hi plane / xb planes
  char* slot1 = alloc((size_t)NT * 256 * 4);
  u16* hsph = (u16*)slot1;          u16* hspl = hsph + (size_t)NT * 256;
  u16* attnh = hsph;
  u16* xbh = hsph;                  u16* xbl = hspl;
  // slot2 (8.4 MB): emb bf16 plane / aout fp32
  char* slot2 = alloc((size_t)NT * 256 * 4);
  u16* embh = (u16*)slot2;
  float* aout = (float*)slot2;
  // slot3 (8.4 MB): off+loc / mout fp32
  char* slot3 = alloc((size_t)NT * 256 * 4);
  float* off = (float*)slot3;       float* loc = off + (size_t)NT * 32;
  float* mout = (float*)slot3;
  // slot4 (16.8 MB): qb fp32 + EKV bf16 / h1 bf16 [NT,1024] (16 MB)
  char* slot4 = alloc((size_t)NT * 256 * 8);
  float* qb = (float*)slot4;
  u16* EKV = (u16*)(slot4 + (size_t)NT * 256 * 4);   // [NT,512] packed bf16
  u16* h1 = (u16*)slot4;                             // [NT,1024] bf16 plane
  if ((size_t)(w - (char*)d_ws) > ws_size) return;

  // ALL prep in one dispatch
  prepall_k<<<1794, 256, 0, stream>>>(hs, emb, Woff, boff, Wq, Wk, Wv, Wo, W1, W2,
                                      Wkvp, bkvp, bk, bv,
                                      hsph, hspl, embh, off, loc,
                                      qkvoTh, qkvoTl, W1Th, W1Tl, W2Th, W2Tl, kvc);

  // grouped q (3-pass) + EKV (2-pass), r13 per-BK staging
  qekv_k<<<1536, 256, 0, stream>>>(hsph, hspl, WqTh, WqTl, bq,
                                   embh, kvWh, kvWl, qb, EKV);

  // gather + dual-chain online-softmax attention
  attn_k<<<2048, 256, 0, stream>>>(qb, EKV, off, loc, kvc, attnh);

  // out-proj (1-pass), LN1, MLP, LN2
  gemm_k<64, 1, 1, 0><<<dim3(128, 4), 256, 0, stream>>>(attnh, nullptr, WoTh, nullptr, bo, aout, NT, 256, 256);
  ln_k<0, 1><<<2048, 256, 0, stream>>>(hs, nullptr, aout, ln1s, ln1b, xbh, xbl);
  gemm128_k<<<dim3(64, 8), 256, 0, stream>>>(xbh, W1Th, b1, h1, NT, 1024, 256);
  gemm_k<64, 1, 1, 0><<<dim3(128, 4), 256, 0, stream>>>(h1, nullptr, W2Th, nullptr, b2, mout, NT, 256, 1024);
  ln_k<1, 0><<<2048, 256, 0, stream>>>(xbh, xbl, mout, ln2s, ln2b, d_out, nullptr);
}

// Round 17
// 243.660 us; speedup vs baseline: 1.0370x; 1.0370x over previous
//
#include <hip/hip_runtime.h>

// Problem dims
#define NT 8192      // N*H*W tokens
#define DM 256
#define HH 64
#define WW 64

typedef unsigned short u16;
typedef __attribute__((ext_vector_type(8))) short short8;  // 8 x bf16 mfma frag
typedef __attribute__((ext_vector_type(4))) float f4;

__device__ __forceinline__ float bf2f(u16 u){
  union { unsigned int i; float f; } v; v.i = ((unsigned int)u) << 16; return v.f;
}
__device__ __forceinline__ u16 f2bf(float f){
  union { float f; unsigned int i; } v; v.f = f;
  unsigned int r = (v.i + 0x7fffu + ((v.i >> 16) & 1u)) >> 16;
  return (u16)r;
}
// wave-uniform scalar promotion (value must be uniform; exact)
__device__ __forceinline__ float rfl(float f){
  return __uint_as_float(__builtin_amdgcn_readfirstlane(__float_as_uint(f)));
}
// async global->LDS 16B (direct DMA, no VGPR round trip)
__device__ __forceinline__ void gld16(const void* g, void* l){
  __builtin_amdgcn_global_load_lds(
      (const __attribute__((address_space(1))) unsigned int*)g,
      (__attribute__((address_space(3))) unsigned int*)l, 16, 0, 0);
}

// ---------------------------------------------------------------------------
// ALL prep in ONE dispatch (1794 blocks) — r13, proven clean:
//  b < 1024: prolog path — per 8 tokens: offsets GEMV + hs->hi/lo + emb->hi
//  1024..1279: qkvo transposes; 1280..1535: W1^T; 1536..1791: W2^T;
//  1792/1793: fold W_kvp/b_kvp through Wk/Wv -> kvc.
// ---------------------------------------------------------------------------
__global__ __launch_bounds__(256) void prepall_k(const float* __restrict__ hs,
                                                 const float* __restrict__ emb,
                                                 const float* __restrict__ Woff,
                                                 const float* __restrict__ boff,
                                                 const float* __restrict__ Wq,
                                                 const float* __restrict__ Wk,
                                                 const float* __restrict__ Wv,
                                                 const float* __restrict__ Wo,
                                                 const float* __restrict__ W1,
                                                 const float* __restrict__ W2,
                                                 const float* __restrict__ Wkvp,
                                                 const float* __restrict__ bkvp,
                                                 const float* __restrict__ bk,
                                                 const float* __restrict__ bv,
                                                 u16* __restrict__ hsph,
                                                 u16* __restrict__ hspl,
                                                 u16* __restrict__ embh,
                                                 float* __restrict__ off,
                                                 float* __restrict__ loc,
                                                 u16* __restrict__ qkvoTh,
                                                 u16* __restrict__ qkvoTl,
                                                 u16* __restrict__ W1Th,
                                                 u16* __restrict__ W1Tl,
                                                 u16* __restrict__ W2Th,
                                                 u16* __restrict__ W2Tl,
                                                 float* __restrict__ kvc){
  __shared__ float smem[10240];
  const int blk = blockIdx.x;
  const int tid = threadIdx.x;
  if (blk < 1024){
    // ---- prolog path ----
    float* hsl = smem;          // [2048]
    float* wl  = smem + 2048;   // [8192]
    const int t0 = blk * 8;
    for (int i = tid; i < 8192; i += 256) wl[i] = Woff[i];
    for (int i = tid; i < 2048; i += 256) hsl[i] = hs[(size_t)t0 * 256 + i];
    __syncthreads();
    {
      const int g = tid >> 5, o = tid & 31;
      float acc = 0.f;
      #pragma unroll 8
      for (int d = 0; d < 256; d++) acc += hsl[g * 256 + d] * wl[d * 32 + o];
      acc += boff[o];
      float sg = 1.f / (1.f + expf(-acc));
      float of = 60.f * sg - 30.f;
      int tok = t0 + g;
      int hh = (tok >> 6) & 63, ww = tok & 63;
      float base = (o & 1) ? (float)ww : (float)hh;
      float l = fminf(fmaxf(base + of, 0.f), 63.f);
      off[tok * 32 + o] = of;
      loc[tok * 32 + o] = l;
    }
    for (int c = tid; c < 512; c += 256){
      f4 v = *(const f4*)&hsl[c * 4];
      ushort4 h, l;
      h.x = f2bf(v.x); l.x = f2bf(v.x - bf2f(h.x));
      h.y = f2bf(v.y); l.y = f2bf(v.y - bf2f(h.y));
      h.z = f2bf(v.z); l.z = f2bf(v.z - bf2f(h.z));
      h.w = f2bf(v.w); l.w = f2bf(v.w - bf2f(h.w));
      ((ushort4*)hsph)[(size_t)t0 * 64 + c] = h;
      ((ushort4*)hspl)[(size_t)t0 * 64 + c] = l;
      f4 e = ((const f4*)emb)[(size_t)t0 * 64 + c];
      ushort4 eh;
      eh.x = f2bf(e.x); eh.y = f2bf(e.y); eh.z = f2bf(e.z); eh.w = f2bf(e.w);
      ((ushort4*)embh)[(size_t)t0 * 64 + c] = eh;
    }
    return;
  }
  const int b = blk - 1024;
  if (b >= 768){               // prepkv fold
    const float* Wx = (b == 768) ? Wk : Wv;
    const float* bx = (b == 768) ? bk : bv;
    float* o = kvc + (b - 768) * 768;
    int e = tid;
    float a0 = 0.f, a1 = 0.f, ab = 0.f;
    for (int d = 0; d < 256; d++){
      float w = Wx[d * 256 + e];
      a0 += Wkvp[d] * w;
      a1 += Wkvp[256 + d] * w;
      ab += bkvp[d] * w;
    }
    o[e] = a0; o[256 + e] = a1; o[512 + e] = ab + bx[e];
    return;
  }
  // ---- weight transpose path ----
  float (*t)[33] = (float(*)[33])smem;
  const float* src; u16 *dh, *dl; int R, C, c0, r0;
  if (b < 256){
    int mat = b >> 6, tt = b & 63;
    src = mat == 0 ? Wq : mat == 1 ? Wk : mat == 2 ? Wv : Wo;
    dh = qkvoTh + mat * 65536; dl = qkvoTl + mat * 65536;
    R = 256; C = 256; c0 = (tt & 7) * 32; r0 = (tt >> 3) * 32;
  } else if (b < 512){
    int tt = b - 256; src = W1; dh = W1Th; dl = W1Tl; R = 256; C = 1024;
    c0 = (tt & 31) * 32; r0 = (tt >> 5) * 32;
  } else {
    int tt = b - 512; src = W2; dh = W2Th; dl = W2Tl; R = 1024; C = 256;
    c0 = (tt & 7) * 32; r0 = (tt >> 3) * 32;
  }
  int tx = tid & 31, ty = tid >> 5;
  for (int i = ty; i < 32; i += 8) t[i][tx] = src[(size_t)(r0 + i) * C + c0 + tx];
  __syncthreads();
  for (int i = ty; i < 32; i += 8){
    float x = t[tx][i];
    u16 h = f2bf(x);
    size_t idx = (size_t)(c0 + i) * R + r0 + tx;
    dh[idx] = h;
    dl[idx] = f2bf(x - bf2f(h));
  }
}

// ---------------------------------------------------------------------------
// Grouped q + EKV GEMM, ONE dispatch (1536 blocks), BM=BN=64, BK=64, K=256.
// r13-proven per-BK staging (32 KB LDS, 5 blocks/CU).
//  blocks 0..511:    q   = hs(hi/lo, 3-pass) x WqT(hi/lo) + bq -> fp32 qb
//  blocks 512..1535: EKV = emb(hi, 2-pass)  x kvWT(hi/lo)      -> packed bf16
// ---------------------------------------------------------------------------
__global__ __launch_bounds__(256) void qekv_k(const u16* __restrict__ hsph,
                                              const u16* __restrict__ hspl,
                                              const u16* __restrict__ WqTh,
                                              const u16* __restrict__ WqTl,
                                              const float* __restrict__ bq,
                                              const u16* __restrict__ embh,
                                              const u16* __restrict__ kvWh,
                                              const u16* __restrict__ kvWl,
                                              float* __restrict__ qb,
                                              u16* __restrict__ EKV){
  __shared__ __align__(16) u16 Ah[8][64][8];
  __shared__ __align__(16) u16 Al[8][64][8];
  __shared__ __align__(16) u16 Bh[8][64][8];
  __shared__ __align__(16) u16 Bl[8][64][8];
  const int bid = blockIdx.x;
  const bool isQ = bid < 512;
  const int b2 = isQ ? bid : bid - 512;
  const int m0 = (b2 & 127) << 6;
  const int n0 = (b2 >> 7) << 6;
  const int K = 256;
  const u16* Agh = isQ ? hsph : embh;
  const u16* Bgh = isQ ? WqTh : kvWh;
  const u16* Bgl = isQ ? WqTl : kvWl;
  const int tid = threadIdx.x;
  const int lane = tid & 63, wave = tid >> 6;
  const int quad = lane >> 4, l15 = lane & 15;
  const int wm = (wave >> 1) << 5, wn = (wave & 1) << 5;
  const int ar = tid & 63, aq = tid >> 6;
  const u16* gAh = Agh + (size_t)(m0 + ar) * K + aq * 8;
  const u16* gAl = hspl + (size_t)(m0 + ar) * K + aq * 8;   // only read if isQ
  const u16* gBh = Bgh + (size_t)(n0 + ar) * K + aq * 8;
  const u16* gBl = Bgl + (size_t)(n0 + ar) * K + aq * 8;
  f4 acc[2][2] = {};
  for (int k0 = 0; k0 < K; k0 += 64){
    __syncthreads();
    gld16(gAh + k0,      &Ah[aq][ar][0]);
    gld16(gAh + k0 + 32, &Ah[aq + 4][ar][0]);
    if (isQ){
      gld16(gAl + k0,      &Al[aq][ar][0]);
      gld16(gAl + k0 + 32, &Al[aq + 4][ar][0]);
    }
    gld16(gBh + k0,      &Bh[aq][ar][0]);
    gld16(gBh + k0 + 32, &Bh[aq + 4][ar][0]);
    gld16(gBl + k0,      &Bl[aq][ar][0]);
    gld16(gBl + k0 + 32, &Bl[aq + 4][ar][0]);
    asm volatile("s_waitcnt vmcnt(0)" ::: "memory");
    __syncthreads();
    #pragma unroll
    for (int kh = 0; kh < 2; kh++){
      const int q = kh * 4 + quad;
      short8 ahf[2], alf[2], bhf[2], blf[2];
      #pragma unroll
      for (int i = 0; i < 2; i++){
        ahf[i] = *(const short8*)(&Ah[q][wm + i * 16 + l15][0]);
        bhf[i] = *(const short8*)(&Bh[q][wn + i * 16 + l15][0]);
        blf[i] = *(const short8*)(&Bl[q][wn + i * 16 + l15][0]);
      }
      if (isQ){
        #pragma unroll
        for (int i = 0; i < 2; i++)
          alf[i] = *(const short8*)(&Al[q][wm + i * 16 + l15][0]);
      }
      #pragma unroll
      for (int mi = 0; mi < 2; mi++)
      #pragma unroll
      for (int ni = 0; ni < 2; ni++){
        if (isQ)
          acc[mi][ni] = __builtin_amdgcn_mfma_f32_16x16x32_bf16(alf[mi], bhf[ni], acc[mi][ni], 0, 0, 0);
        acc[mi][ni] = __builtin_amdgcn_mfma_f32_16x16x32_bf16(ahf[mi], blf[ni], acc[mi][ni], 0, 0, 0);
        acc[mi][ni] = __builtin_amdgcn_mfma_f32_16x16x32_bf16(ahf[mi], bhf[ni], acc[mi][ni], 0, 0, 0);
      }
    }
  }
  #pragma unroll
  for (int mi = 0; mi < 2; mi++)
  #pragma unroll
  for (int ni = 0; ni < 2; ni++){
    int col = n0 + wn + ni * 16 + l15;
    int rowb = m0 + wm + mi * 16 + quad * 4;
    if (isQ){
      float bval = bq[col];
      #pragma unroll
      for (int rg = 0; rg < 4; rg++)
        qb[(size_t)(rowb + rg) * 256 + col] = acc[mi][ni][rg] + bval;
    } else {
      int part = col >> 8, d = col & 255;
      int pc = ((d >> 2) << 3) + (part << 2) + (d & 3);
      #pragma unroll
      for (int rg = 0; rg < 4; rg++)
        EKV[(size_t)(rowb + rg) * 512 + pc] = f2bf(acc[mi][ni][rg]);
    }
  }
}

// ---------------------------------------------------------------------------
// Split-precision MFMA GEMM (r13 template) — O-proj (K=256) + W2 (K=1024).
// APREC/BPREC: 2 = hi/lo planes, 1 = hi only.
// EPI 0: fp32 +bias -> C0.   EPI 1: gelu(tanh) -> bf16 plane C0.
// ---------------------------------------------------------------------------
template<int BN, int APREC, int BPREC, int EPI>
__global__ __launch_bounds__(256) void gemm_k(const u16* __restrict__ Agh,
                                              const u16* __restrict__ Agl,
                                              const u16* __restrict__ Bgh,
                                              const u16* __restrict__ Bgl,
                                              const float* __restrict__ bias,
                                              void* __restrict__ C0,
                                              int M, int N, int K){
  constexpr int NF = BN / 32;
  __shared__ __align__(16) u16 Ah[8][64][8];
  __shared__ __align__(16) u16 Al[APREC == 2 ? 8 : 1][64][8];
  __shared__ __align__(16) u16 Bh[8][BN][8];
  __shared__ __align__(16) u16 Bl[BPREC == 2 ? 8 : 1][BN][8];
  const int m0 = blockIdx.x << 6, n0 = blockIdx.y * BN;
  const int tid = threadIdx.x;
  const int lane = tid & 63, wave = tid >> 6;
  const int quad = lane >> 4, l15 = lane & 15;
  const int wm = (wave >> 1) << 5;
  const int wn = (wave & 1) * (BN >> 1);
  const int ar = tid & 63, aq = tid >> 6;
  const u16* gAh = Agh + (size_t)(m0 + ar) * K + aq * 8;
  const u16* gAl = (APREC == 2) ? (Agl + (size_t)(m0 + ar) * K + aq * 8) : nullptr;
  const int br = (BN == 128) ? (tid & 127) : (tid & 63);
  const int bq = (BN == 128) ? (tid >> 7) : (tid >> 6);
  const u16* gBh = Bgh + (size_t)(n0 + br) * K + bq * 8;
  const u16* gBl = (BPREC == 2) ? (Bgl + (size_t)(n0 + br) * K + bq * 8) : nullptr;
  f4 acc[2][NF] = {};
  for (int k0 = 0; k0 < K; k0 += 64){
    __syncthreads();
    gld16(gAh + k0,      &Ah[aq][ar][0]);
    gld16(gAh + k0 + 32, &Ah[aq + 4][ar][0]);
    if (APREC == 2){
      gld16(gAl + k0,      &Al[aq][ar][0]);
      gld16(gAl + k0 + 32, &Al[aq + 4][ar][0]);
    }
    gld16(gBh + k0,      &Bh[bq][br][0]);
    gld16(gBh + k0 + 32, &Bh[bq + 4][br][0]);
    if (BPREC == 2){
      gld16(gBl + k0,      &Bl[bq][br][0]);
      gld16(gBl + k0 + 32, &Bl[bq + 4][br][0]);
    }
    asm volatile("s_waitcnt vmcnt(0)" ::: "memory");
    __syncthreads();
    #pragma unroll
    for (int kh = 0; kh < 2; kh++){
      const int q = kh * 4 + quad;
      short8 ahf[2], alf[2], bhf[NF], blf[NF];
      #pragma unroll
      for (int i = 0; i < 2; i++){
        ahf[i] = *(const short8*)(&Ah[q][wm + i * 16 + l15][0]);
        if (APREC == 2) alf[i] = *(const short8*)(&Al[q][wm + i * 16 + l15][0]);
      }
      #pragma unroll
      for (int i = 0; i < NF; i++){
        bhf[i] = *(const short8*)(&Bh[q][wn + i * 16 + l15][0]);
        if (BPREC == 2) blf[i] = *(const short8*)(&Bl[q][wn + i * 16 + l15][0]);
      }
      #pragma unroll
      for (int mi = 0; mi < 2; mi++)
      #pragma unroll
      for (int ni = 0; ni < NF; ni++){
        if (APREC == 2)
          acc[mi][ni] = __builtin_amdgcn_mfma_f32_16x16x32_bf16(alf[mi], bhf[ni], acc[mi][ni], 0, 0, 0);
        if (BPREC == 2)
          acc[mi][ni] = __builtin_amdgcn_mfma_f32_16x16x32_bf16(ahf[mi], blf[ni], acc[mi][ni], 0, 0, 0);
        acc[mi][ni] = __builtin_amdgcn_mfma_f32_16x16x32_bf16(ahf[mi], bhf[ni], acc[mi][ni], 0, 0, 0);
      }
    }
  }
  #pragma unroll
  for (int mi = 0; mi < 2; mi++)
  #pragma unroll
  for (int ni = 0; ni < NF; ni++){
    int col = n0 + wn + ni * 16 + l15;
    float bval = bias ? bias[col] : 0.f;
    int rowb = m0 + wm + mi * 16 + quad * 4;
    #pragma unroll
    for (int rg = 0; rg < 4; rg++){
      float v = acc[mi][ni][rg] + bval;
      int row = rowb + rg;
      if (EPI == 0){
        ((float*)C0)[(size_t)row * N + col] = v;
      } else {
        float t = v + 0.044715f * v * v * v;
        float g = 0.5f * v * (1.f + tanhf(0.7978845608f * t));
        ((u16*)C0)[(size_t)row * N + col] = f2bf(g);
      }
    }
  }
}

// ---------------------------------------------------------------------------
// Dedicated W1 GEMM: 128x128 tile, BK=64, A bf16 plane, B hi plane (1-pass),
// gelu -> bf16. Proven clean (r10).
// ---------------------------------------------------------------------------
__global__ __launch_bounds__(256) void gemm128_k(const u16* __restrict__ Agh,
                                                 const u16* __restrict__ Bgh,
                                                 const float* __restrict__ bias,
                                                 u16* __restrict__ C0,
                                                 int M, int N, int K){
  __shared__ __align__(16) u16 Ah[8][128][8];
  __shared__ __align__(16) u16 Bh[8][128][8];
  const int m0 = blockIdx.x << 7, n0 = blockIdx.y << 7;
  const int tid = threadIdx.x;
  const int lane = tid & 63, wave = tid >> 6;
  const int quad = lane >> 4, l15 = lane & 15;
  const int wm = (wave >> 1) << 6, wn = (wave & 1) << 6;
  const int ar = tid & 127, q0 = tid >> 7;
  const u16* gA  = Agh + (size_t)(m0 + ar) * K + q0 * 8;
  const u16* gBhp = Bgh + (size_t)(n0 + ar) * K + q0 * 8;
  f4 acc[4][4] = {};
  for (int k0 = 0; k0 < K; k0 += 64){
    __syncthreads();
    #pragma unroll
    for (int j = 0; j < 4; j++){
      gld16(gA   + k0 + j * 16, &Ah[q0 + 2 * j][ar][0]);
      gld16(gBhp + k0 + j * 16, &Bh[q0 + 2 * j][ar][0]);
    }
    asm volatile("s_waitcnt vmcnt(0)" ::: "memory");
    __syncthreads();
    #pragma unroll
    for (int kh = 0; kh < 2; kh++){
      const int q = kh * 4 + quad;
      short8 af[4], bh8[4];
      #pragma unroll
      for (int i = 0; i < 4; i++){
        af[i]  = *(const short8*)(&Ah[q][wm + i * 16 + l15][0]);
        bh8[i] = *(const short8*)(&Bh[q][wn + i * 16 + l15][0]);
      }
      #pragma unroll
      for (int mi = 0; mi < 4; mi++)
      #pragma unroll
      for (int ni = 0; ni < 4; ni++)
        acc[mi][ni] = __builtin_amdgcn_mfma_f32_16x16x32_bf16(af[mi], bh8[ni], acc[mi][ni], 0, 0, 0);
    }
  }
  #pragma unroll
  for (int mi = 0; mi < 4; mi++)
  #pragma unroll
  for (int ni = 0; ni < 4; ni++){
    int col = n0 + wn + ni * 16 + l15;
    float bval = bias[col];
    int rowb = m0 + wm + mi * 16 + quad * 4;
    #pragma unroll
    for (int rg = 0; rg < 4; rg++){
      float v = acc[mi][ni][rg] + bval;
      float t = v + 0.044715f * v * v * v;
      float g = 0.5f * v * (1.f + tanhf(0.7978845608f * t));
      C0[(size_t)(rowb + rg) * N + col] = f2bf(g);
    }
  }
}

// ---------------------------------------------------------------------------
// Attention — r13 online-softmax loop with WAVE-UNIFORM SCALARIZATION:
// loc/off/corner-indices are identical across all 64 lanes; readfirstlane
// promotes them to SGPRs so address math + interp weights run on the scalar
// unit and each gather is s-base + lane*16 (1 VALU inst). Numerics identical.
// ---------------------------------------------------------------------------
__device__ __forceinline__ void unpack8(int4 p, f4& k4, f4& v4){
  k4.x = bf2f((u16)(p.x & 0xffff)); k4.y = bf2f((u16)((unsigned)p.x >> 16));
  k4.z = bf2f((u16)(p.y & 0xffff)); k4.w = bf2f((u16)((unsigned)p.y >> 16));
  v4.x = bf2f((u16)(p.z & 0xffff)); v4.y = bf2f((u16)((unsigned)p.z >> 16));
  v4.z = bf2f((u16)(p.w & 0xffff)); v4.w = bf2f((u16)((unsigned)p.w >> 16));
}

__global__ __launch_bounds__(256) void attn_k(const float* __restrict__ q,
                                              const u16* __restrict__ EKV,
                                              const float* __restrict__ offb,
                                              const float* __restrict__ locb,
                                              const float* __restrict__ kvc,
                                              u16* __restrict__ ah){
  const int tid = threadIdx.x;
  const int wave = tid >> 6, lane = tid & 63;
  const int tok = blockIdx.x * 4 + wave;
  const int base = (tok >> 12) << 12;   // n*4096
  const int4* E = (const int4*)EKV;     // 16B per (row,lane)
  const f4* kvc4 = (const f4*)kvc;
  f4 qv  = *((const f4*)q + (size_t)tok * 64 + lane);
  f4 wk0 = kvc4[lane], wk1 = kvc4[64 + lane], bkv = kvc4[128 + lane];
  f4 wv0 = kvc4[192 + lane], wv1 = kvc4[256 + lane], bvv = kvc4[320 + lane];
  float m = -1e30f, l = 0.f;
  f4 acc = {0.f, 0.f, 0.f, 0.f};
  #pragma unroll
  for (int s = 0; s < 16; s++){
    // wave-uniform sample parameters -> SGPRs
    float y  = rfl(locb[tok * 32 + s * 2]);
    float x  = rfl(locb[tok * 32 + s * 2 + 1]);
    float o0 = rfl(offb[tok * 32 + s * 2]);
    float o1 = rfl(offb[tok * 32 + s * 2 + 1]);
    float yf = floorf(y), xf = floorf(x);
    int y0 = (int)yf, x0 = (int)xf;
    int y1 = min(y0 + 1, 63), x1 = min(x0 + 1, 63);
    float wy = y - yf, wx = x - xf;
    // scalar corner row indices; loads become s-base + lane*16
    const int4* p00p = E + (size_t)(base + y0 * 64 + x0) * 64;
    const int4* p01p = E + (size_t)(base + y0 * 64 + x1) * 64;
    const int4* p10p = E + (size_t)(base + y1 * 64 + x0) * 64;
    const int4* p11p = E + (size_t)(base + y1 * 64 + x1) * 64;
    int4 p00 = p00p[lane];
    int4 p01 = p01p[lane];
    int4 p10 = p10p[lane];
    int4 p11 = p11p[lane];
    f4 k00, v00, k01, v01, k10, v10, k11, v11;
    unpack8(p00, k00, v00); unpack8(p01, k01, v01);
    unpack8(p10, k10, v10); unpack8(p11, k11, v11);
    float w00 = (1.f - wy) * (1.f - wx), w01 = (1.f - wy) * wx;
    float w10 = wy * (1.f - wx), w11 = wy * wx;
    f4 kk = w00 * k00 + w01 * k01 + w10 * k10 + w11 * k11;
    f4 vv = w00 * v00 + w01 * v01 + w10 * v10 + w11 * v11;
    kk += o0 * wk0 + o1 * wk1 + bkv;
    vv += o0 * wv0 + o1 * wv1 + bvv;
    float p = qv.x * kk.x + qv.y * kk.y + qv.z * kk.z + qv.w * kk.w;
    p += __shfl_xor(p, 1); p += __shfl_xor(p, 2);
    p += __shfl_xor(p, 4); p += __shfl_xor(p, 8);
    p *= 0.125f;   // /sqrt(64)
    float mn = fmaxf(m, p);
    float cor = __expf(m - mn);
    float wgt = __expf(p - mn);
    l = l * cor + wgt;
    acc = acc * cor + wgt * vv;
    m = mn;
  }
  float inv = 1.f / l;
  f4 o = acc * inv;
  ushort4 h;
  h.x = f2bf(o.x); h.y = f2bf(o.y); h.z = f2bf(o.z); h.w = f2bf(o.w);
  *(ushort4*)(ah + (size_t)tok * 256 + lane * 4) = h;
}

// ---------------------------------------------------------------------------
// LayerNorm(a + b) * scale + bias. One wave per token.
// INP: 0 -> a0 fp32; 1 -> a0/a1 hi/lo planes.  OUTP: 0 -> fp32; 1 -> planes.
// ---------------------------------------------------------------------------
template<int INP, int OUTP>
__global__ __launch_bounds__(256) void ln_k(const void* __restrict__ a0,
                                            const void* __restrict__ a1,
                                            const float* __restrict__ b,
                                            const float* __restrict__ sc,
                                            const float* __restrict__ bi,
                                            void* __restrict__ o0,
                                            void* __restrict__ o1){
  const int tid = threadIdx.x;
  const int wave = tid >> 6, lane = tid & 63;
  const int tok = blockIdx.x * 4 + wave;
  float x0, x1, x2, x3;
  if (INP){
    ushort4 h = ((const ushort4*)a0)[(size_t)tok * 64 + lane];
    ushort4 lo = ((const ushort4*)a1)[(size_t)tok * 64 + lane];
    x0 = bf2f(h.x) + bf2f(lo.x); x1 = bf2f(h.y) + bf2f(lo.y);
    x2 = bf2f(h.z) + bf2f(lo.z); x3 = bf2f(h.w) + bf2f(lo.w);
  } else {
    f4 av = ((const f4*)a0)[(size_t)tok * 64 + lane];
    x0 = av.x; x1 = av.y; x2 = av.z; x3 = av.w;
  }
  f4 bv = ((const f4*)b)[(size_t)tok * 64 + lane];
  x0 += bv.x; x1 += bv.y; x2 += bv.z; x3 += bv.w;
  float sm = x0 + x1 + x2 + x3;
  float sq = x0 * x0 + x1 * x1 + x2 * x2 + x3 * x3;
  #pragma unroll
  for (int mm = 1; mm < 64; mm <<= 1){ sm += __shfl_xor(sm, mm); sq += __shfl_xor(sq, mm); }
  float mean = sm * (1.f / 256.f);
  float var = sq * (1.f / 256.f) - mean * mean;
  float rs = rsqrtf(var + 1e-6f);
  f4 sv = ((const f4*)sc)[lane];
  f4 bb = ((const f4*)bi)[lane];
  float y0 = (x0 - mean) * rs * sv.x + bb.x;
  float y1 = (x1 - mean) * rs * sv.y + bb.y;
  float y2 = (x2 - mean) * rs * sv.z + bb.z;
  float y3 = (x3 - mean) * rs * sv.w + bb.w;
  if (OUTP){
    ushort4 h, lo;
    h.x = f2bf(y0); lo.x = f2bf(y0 - bf2f(h.x));
    h.y = f2bf(y1); lo.y = f2bf(y1 - bf2f(h.y));
    h.z = f2bf(y2); lo.z = f2bf(y2 - bf2f(h.z));
    h.w = f2bf(y3); lo.w = f2bf(y3 - bf2f(h.w));
    ((ushort4*)o0)[(size_t)tok * 64 + lane] = h;
    ((ushort4*)o1)[(size_t)tok * 64 + lane] = lo;
  } else {
    f4 ov = {y0, y1, y2, y3};
    ((f4*)o0)[(size_t)tok * 64 + lane] = ov;
  }
}

// ---------------------------------------------------------------------------
extern "C" void kernel_launch(void* const* d_in, const int* in_sizes, int n_in,
                              void* d_out, int out_size, void* d_ws, size_t ws_size,
                              hipStream_t stream){
  const float* hs   = (const float*)d_in[0];
  const float* emb  = (const float*)d_in[1];
  const float* Woff = (const float*)d_in[2];
  const float* boff = (const float*)d_in[3];
  const float* Wkvp = (const float*)d_in[4];
  const float* bkvp = (const float*)d_in[5];
  const float* Wq   = (const float*)d_in[6];
  const float* bq   = (const float*)d_in[7];
  const float* Wk   = (const float*)d_in[8];
  const float* bk   = (const float*)d_in[9];
  const float* Wv   = (const float*)d_in[10];
  const float* bv   = (const float*)d_in[11];
  const float* Wo   = (const float*)d_in[12];
  const float* bo   = (const float*)d_in[13];
  const float* ln1s = (const float*)d_in[14];
  const float* ln1b = (const float*)d_in[15];
  const float* ln2s = (const float*)d_in[16];
  const float* ln2b = (const float*)d_in[17];
  const float* W1   = (const float*)d_in[18];
  const float* b1   = (const float*)d_in[19];
  const float* W2   = (const float*)d_in[20];
  const float* b2   = (const float*)d_in[21];

  char* w = (char*)d_ws;
  auto alloc = [&](size_t bytes){ char* p = w; w += (bytes + 255) & ~(size_t)255; return p; };
  // weight planes: [WqT | WkT | WvT | WoT] contiguous hi and lo
  u16* qkvoTh = (u16*)alloc(4 * 65536 * 2);
  u16* qkvoTl = (u16*)alloc(4 * 65536 * 2);
  u16* WqTh = qkvoTh;              u16* WqTl = qkvoTl;
  u16* kvWh = qkvoTh + 65536;      u16* kvWl = qkvoTl + 65536;   // [512,256]
  u16* WoTh = qkvoTh + 3 * 65536;
  u16* W1Th = (u16*)alloc(262144 * 2); u16* W1Tl = (u16*)alloc(262144 * 2);
  u16* W2Th = (u16*)alloc(262144 * 2); u16* W2Tl = (u16*)alloc(262144 * 2);
  float* kvc = (float*)alloc(1536 * 4);
  // slot1 (8.4 MB): hs hi/lo planes / attn hi plane / xb planes
  char* slot1 = alloc((size_t)NT * 256 * 4);
  u16* hsph = (u16*)slot1;          u16* hspl = hsph + (size_t)NT * 256;
  u16* attnh = hsph;
  u16* xbh = hsph;                  u16* xbl = hspl;
  // slot2 (8.4 MB): emb bf16 plane / aout fp32
  char* slot2 = alloc((size_t)NT * 256 * 4);
  u16* embh = (u16*)slot2;
  float* aout = (float*)slot2;
  // slot3 (8.4 MB): off+loc / mout fp32
  char* slot3 = alloc((size_t)NT * 256 * 4);
  float* off = (float*)slot3;       float* loc = off + (size_t)NT * 32;
  float* mout = (float*)slot3;
  // slot4 (16.8 MB): qb fp32 + EKV bf16 / h1 bf16 [NT,1024] (16 MB)
  char* slot4 = alloc((size_t)NT * 256 * 8);
  float* qb = (float*)slot4;
  u16* EKV = (u16*)(slot4 + (size_t)NT * 256 * 4);   // [NT,512] packed bf16
  u16* h1 = (u16*)slot4;                             // [NT,1024] bf16 plane
  if ((size_t)(w - (char*)d_ws) > ws_size) return;

  // ALL prep in one dispatch
  prepall_k<<<1794, 256, 0, stream>>>(hs, emb, Woff, boff, Wq, Wk, Wv, Wo, W1, W2,
                                      Wkvp, bkvp, bk, bv,
                                      hsph, hspl, embh, off, loc,
                                      qkvoTh, qkvoTl, W1Th, W1Tl, W2Th, W2Tl, kvc);

  // grouped q (3-pass) + EKV (2-pass), r13 per-BK staging
  qekv_k<<<1536, 256, 0, stream>>>(hsph, hspl, WqTh, WqTl, bq,
                                   embh, kvWh, kvWl, qb, EKV);

  // gather + online-softmax attention (scalarized addresses/weights)
  attn_k<<<2048, 256, 0, stream>>>(qb, EKV, off, loc, kvc, attnh);

  // out-proj (1-pass), LN1, MLP, LN2
  gemm_k<64, 1, 1, 0><<<dim3(128, 4), 256, 0, stream>>>(attnh, nullptr, WoTh, nullptr, bo, aout, NT, 256, 256);
  ln_k<0, 1><<<2048, 256, 0, stream>>>(hs, nullptr, aout, ln1s, ln1b, xbh, xbl);
  gemm128_k<<<dim3(64, 8), 256, 0, stream>>>(xbh, W1Th, b1, h1, NT, 1024, 256);
  gemm_k<64, 1, 1, 0><<<dim3(128, 4), 256, 0, stream>>>(h1, nullptr, W2Th, nullptr, b2, mout, NT, 256, 1024);
  ln_k<1, 0><<<2048, 256, 0, stream>>>(xbh, xbl, mout, ln2s, ln2b, d_out, nullptr);
}

// Round 18
// 241.162 us; speedup vs baseline: 1.0477x; 1.0104x over previous
//
#include <hip/hip_runtime.h>

// Problem dims
#define NT 8192      // N*H*W tokens
#define DM 256
#define HH 64
#define WW 64

typedef unsigned short u16;
typedef __attribute__((ext_vector_type(8))) short short8;  // 8 x bf16 mfma frag
typedef __attribute__((ext_vector_type(4))) float f4;

__device__ __forceinline__ float bf2f(u16 u){
  union { unsigned int i; float f; } v; v.i = ((unsigned int)u) << 16; return v.f;
}
__device__ __forceinline__ u16 f2bf(float f){
  union { float f; unsigned int i; } v; v.f = f;
  unsigned int r = (v.i + 0x7fffu + ((v.i >> 16) & 1u)) >> 16;
  return (u16)r;
}
// async global->LDS 16B (direct DMA, no VGPR round trip)
__device__ __forceinline__ void gld16(const void* g, void* l){
  __builtin_amdgcn_global_load_lds(
      (const __attribute__((address_space(1))) unsigned int*)g,
      (__attribute__((address_space(3))) unsigned int*)l, 16, 0, 0);
}

// ---------------------------------------------------------------------------
// ALL prep in ONE dispatch (1794 blocks) — r13, proven clean:
//  b < 1024: prolog path — per 8 tokens: offsets GEMV + hs->hi/lo + emb->hi
//  1024..1279: qkvo transposes; 1280..1535: W1^T; 1536..1791: W2^T;
//  1792/1793: fold W_kvp/b_kvp through Wk/Wv -> kvc.
// ---------------------------------------------------------------------------
__global__ __launch_bounds__(256) void prepall_k(const float* __restrict__ hs,
                                                 const float* __restrict__ emb,
                                                 const float* __restrict__ Woff,
                                                 const float* __restrict__ boff,
                                                 const float* __restrict__ Wq,
                                                 const float* __restrict__ Wk,
                                                 const float* __restrict__ Wv,
                                                 const float* __restrict__ Wo,
                                                 const float* __restrict__ W1,
                                                 const float* __restrict__ W2,
                                                 const float* __restrict__ Wkvp,
                                                 const float* __restrict__ bkvp,
                                                 const float* __restrict__ bk,
                                                 const float* __restrict__ bv,
                                                 u16* __restrict__ hsph,
                                                 u16* __restrict__ hspl,
                                                 u16* __restrict__ embh,
                                                 float* __restrict__ off,
                                                 float* __restrict__ loc,
                                                 u16* __restrict__ qkvoTh,
                                                 u16* __restrict__ qkvoTl,
                                                 u16* __restrict__ W1Th,
                                                 u16* __restrict__ W1Tl,
                                                 u16* __restrict__ W2Th,
                                                 u16* __restrict__ W2Tl,
                                                 float* __restrict__ kvc){
  __shared__ float smem[10240];
  const int blk = blockIdx.x;
  const int tid = threadIdx.x;
  if (blk < 1024){
    // ---- prolog path ----
    float* hsl = smem;          // [2048]
    float* wl  = smem + 2048;   // [8192]
    const int t0 = blk * 8;
    for (int i = tid; i < 8192; i += 256) wl[i] = Woff[i];
    for (int i = tid; i < 2048; i += 256) hsl[i] = hs[(size_t)t0 * 256 + i];
    __syncthreads();
    {
      const int g = tid >> 5, o = tid & 31;
      float acc = 0.f;
      #pragma unroll 8
      for (int d = 0; d < 256; d++) acc += hsl[g * 256 + d] * wl[d * 32 + o];
      acc += boff[o];
      float sg = 1.f / (1.f + expf(-acc));
      float of = 60.f * sg - 30.f;
      int tok = t0 + g;
      int hh = (tok >> 6) & 63, ww = tok & 63;
      float base = (o & 1) ? (float)ww : (float)hh;
      float l = fminf(fmaxf(base + of, 0.f), 63.f);
      off[tok * 32 + o] = of;
      loc[tok * 32 + o] = l;
    }
    for (int c = tid; c < 512; c += 256){
      f4 v = *(const f4*)&hsl[c * 4];
      ushort4 h, l;
      h.x = f2bf(v.x); l.x = f2bf(v.x - bf2f(h.x));
      h.y = f2bf(v.y); l.y = f2bf(v.y - bf2f(h.y));
      h.z = f2bf(v.z); l.z = f2bf(v.z - bf2f(h.z));
      h.w = f2bf(v.w); l.w = f2bf(v.w - bf2f(h.w));
      ((ushort4*)hsph)[(size_t)t0 * 64 + c] = h;
      ((ushort4*)hspl)[(size_t)t0 * 64 + c] = l;
      f4 e = ((const f4*)emb)[(size_t)t0 * 64 + c];
      ushort4 eh;
      eh.x = f2bf(e.x); eh.y = f2bf(e.y); eh.z = f2bf(e.z); eh.w = f2bf(e.w);
      ((ushort4*)embh)[(size_t)t0 * 64 + c] = eh;
    }
    return;
  }
  const int b = blk - 1024;
  if (b >= 768){               // prepkv fold
    const float* Wx = (b == 768) ? Wk : Wv;
    const float* bx = (b == 768) ? bk : bv;
    float* o = kvc + (b - 768) * 768;
    int e = tid;
    float a0 = 0.f, a1 = 0.f, ab = 0.f;
    for (int d = 0; d < 256; d++){
      float w = Wx[d * 256 + e];
      a0 += Wkvp[d] * w;
      a1 += Wkvp[256 + d] * w;
      ab += bkvp[d] * w;
    }
    o[e] = a0; o[256 + e] = a1; o[512 + e] = ab + bx[e];
    return;
  }
  // ---- weight transpose path ----
  float (*t)[33] = (float(*)[33])smem;
  const float* src; u16 *dh, *dl; int R, C, c0, r0;
  if (b < 256){
    int mat = b >> 6, tt = b & 63;
    src = mat == 0 ? Wq : mat == 1 ? Wk : mat == 2 ? Wv : Wo;
    dh = qkvoTh + mat * 65536; dl = qkvoTl + mat * 65536;
    R = 256; C = 256; c0 = (tt & 7) * 32; r0 = (tt >> 3) * 32;
  } else if (b < 512){
    int tt = b - 256; src = W1; dh = W1Th; dl = W1Tl; R = 256; C = 1024;
    c0 = (tt & 31) * 32; r0 = (tt >> 5) * 32;
  } else {
    int tt = b - 512; src = W2; dh = W2Th; dl = W2Tl; R = 1024; C = 256;
    c0 = (tt & 7) * 32; r0 = (tt >> 3) * 32;
  }
  int tx = tid & 31, ty = tid >> 5;
  for (int i = ty; i < 32; i += 8) t[i][tx] = src[(size_t)(r0 + i) * C + c0 + tx];
  __syncthreads();
  for (int i = ty; i < 32; i += 8){
    float x = t[tx][i];
    u16 h = f2bf(x);
    size_t idx = (size_t)(c0 + i) * R + r0 + tx;
    dh[idx] = h;
    dl[idx] = f2bf(x - bf2f(h));
  }
}

// ---------------------------------------------------------------------------
// Grouped q + EKV GEMM, ONE dispatch (1536 blocks), BM=BN=64, BK=64, K=256.
// r13-proven per-BK staging (32 KB LDS, 5 blocks/CU).
//  blocks 0..511:    q   = hs(hi/lo, 3-pass) x WqT(hi/lo) + bq -> fp32 qb
//  blocks 512..1535: EKV = emb(hi, 2-pass)  x kvWT(hi/lo)      -> packed bf16
// ---------------------------------------------------------------------------
__global__ __launch_bounds__(256) void qekv_k(const u16* __restrict__ hsph,
                                              const u16* __restrict__ hspl,
                                              const u16* __restrict__ WqTh,
                                              const u16* __restrict__ WqTl,
                                              const float* __restrict__ bq,
                                              const u16* __restrict__ embh,
                                              const u16* __restrict__ kvWh,
                                              const u16* __restrict__ kvWl,
                                              float* __restrict__ qb,
                                              u16* __restrict__ EKV){
  __shared__ __align__(16) u16 Ah[8][64][8];
  __shared__ __align__(16) u16 Al[8][64][8];
  __shared__ __align__(16) u16 Bh[8][64][8];
  __shared__ __align__(16) u16 Bl[8][64][8];
  const int bid = blockIdx.x;
  const bool isQ = bid < 512;
  const int b2 = isQ ? bid : bid - 512;
  const int m0 = (b2 & 127) << 6;
  const int n0 = (b2 >> 7) << 6;
  const int K = 256;
  const u16* Agh = isQ ? hsph : embh;
  const u16* Bgh = isQ ? WqTh : kvWh;
  const u16* Bgl = isQ ? WqTl : kvWl;
  const int tid = threadIdx.x;
  const int lane = tid & 63, wave = tid >> 6;
  const int quad = lane >> 4, l15 = lane & 15;
  const int wm = (wave >> 1) << 5, wn = (wave & 1) << 5;
  const int ar = tid & 63, aq = tid >> 6;
  const u16* gAh = Agh + (size_t)(m0 + ar) * K + aq * 8;
  const u16* gAl = hspl + (size_t)(m0 + ar) * K + aq * 8;   // only read if isQ
  const u16* gBh = Bgh + (size_t)(n0 + ar) * K + aq * 8;
  const u16* gBl = Bgl + (size_t)(n0 + ar) * K + aq * 8;
  f4 acc[2][2] = {};
  for (int k0 = 0; k0 < K; k0 += 64){
    __syncthreads();
    gld16(gAh + k0,      &Ah[aq][ar][0]);
    gld16(gAh + k0 + 32, &Ah[aq + 4][ar][0]);
    if (isQ){
      gld16(gAl + k0,      &Al[aq][ar][0]);
      gld16(gAl + k0 + 32, &Al[aq + 4][ar][0]);
    }
    gld16(gBh + k0,      &Bh[aq][ar][0]);
    gld16(gBh + k0 + 32, &Bh[aq + 4][ar][0]);
    gld16(gBl + k0,      &Bl[aq][ar][0]);
    gld16(gBl + k0 + 32, &Bl[aq + 4][ar][0]);
    asm volatile("s_waitcnt vmcnt(0)" ::: "memory");
    __syncthreads();
    #pragma unroll
    for (int kh = 0; kh < 2; kh++){
      const int q = kh * 4 + quad;
      short8 ahf[2], alf[2], bhf[2], blf[2];
      #pragma unroll
      for (int i = 0; i < 2; i++){
        ahf[i] = *(const short8*)(&Ah[q][wm + i * 16 + l15][0]);
        bhf[i] = *(const short8*)(&Bh[q][wn + i * 16 + l15][0]);
        blf[i] = *(const short8*)(&Bl[q][wn + i * 16 + l15][0]);
      }
      if (isQ){
        #pragma unroll
        for (int i = 0; i < 2; i++)
          alf[i] = *(const short8*)(&Al[q][wm + i * 16 + l15][0]);
      }
      #pragma unroll
      for (int mi = 0; mi < 2; mi++)
      #pragma unroll
      for (int ni = 0; ni < 2; ni++){
        if (isQ)
          acc[mi][ni] = __builtin_amdgcn_mfma_f32_16x16x32_bf16(alf[mi], bhf[ni], acc[mi][ni], 0, 0, 0);
        acc[mi][ni] = __builtin_amdgcn_mfma_f32_16x16x32_bf16(ahf[mi], blf[ni], acc[mi][ni], 0, 0, 0);
        acc[mi][ni] = __builtin_amdgcn_mfma_f32_16x16x32_bf16(ahf[mi], bhf[ni], acc[mi][ni], 0, 0, 0);
      }
    }
  }
  #pragma unroll
  for (int mi = 0; mi < 2; mi++)
  #pragma unroll
  for (int ni = 0; ni < 2; ni++){
    int col = n0 + wn + ni * 16 + l15;
    int rowb = m0 + wm + mi * 16 + quad * 4;
    if (isQ){
      float bval = bq[col];
      #pragma unroll
      for (int rg = 0; rg < 4; rg++)
        qb[(size_t)(rowb + rg) * 256 + col] = acc[mi][ni][rg] + bval;
    } else {
      int part = col >> 8, d = col & 255;
      int pc = ((d >> 2) << 3) + (part << 2) + (d & 3);
      #pragma unroll
      for (int rg = 0; rg < 4; rg++)
        EKV[(size_t)(rowb + rg) * 512 + pc] = f2bf(acc[mi][ni][rg]);
    }
  }
}

// ---------------------------------------------------------------------------
// Split-precision MFMA GEMM (r13 template) — O-proj (K=256) + W2 (K=1024).
// APREC/BPREC: 2 = hi/lo planes, 1 = hi only.
// EPI 0: fp32 +bias -> C0.   EPI 1: gelu(tanh) -> bf16 plane C0.
// ---------------------------------------------------------------------------
template<int BN, int APREC, int BPREC, int EPI>
__global__ __launch_bounds__(256) void gemm_k(const u16* __restrict__ Agh,
                                              const u16* __restrict__ Agl,
                                              const u16* __restrict__ Bgh,
                                              const u16* __restrict__ Bgl,
                                              const float* __restrict__ bias,
                                              void* __restrict__ C0,
                                              int M, int N, int K){
  constexpr int NF = BN / 32;
  __shared__ __align__(16) u16 Ah[8][64][8];
  __shared__ __align__(16) u16 Al[APREC == 2 ? 8 : 1][64][8];
  __shared__ __align__(16) u16 Bh[8][BN][8];
  __shared__ __align__(16) u16 Bl[BPREC == 2 ? 8 : 1][BN][8];
  const int m0 = blockIdx.x << 6, n0 = blockIdx.y * BN;
  const int tid = threadIdx.x;
  const int lane = tid & 63, wave = tid >> 6;
  const int quad = lane >> 4, l15 = lane & 15;
  const int wm = (wave >> 1) << 5;
  const int wn = (wave & 1) * (BN >> 1);
  const int ar = tid & 63, aq = tid >> 6;
  const u16* gAh = Agh + (size_t)(m0 + ar) * K + aq * 8;
  const u16* gAl = (APREC == 2) ? (Agl + (size_t)(m0 + ar) * K + aq * 8) : nullptr;
  const int br = (BN == 128) ? (tid & 127) : (tid & 63);
  const int bq = (BN == 128) ? (tid >> 7) : (tid >> 6);
  const u16* gBh = Bgh + (size_t)(n0 + br) * K + bq * 8;
  const u16* gBl = (BPREC == 2) ? (Bgl + (size_t)(n0 + br) * K + bq * 8) : nullptr;
  f4 acc[2][NF] = {};
  for (int k0 = 0; k0 < K; k0 += 64){
    __syncthreads();
    gld16(gAh + k0,      &Ah[aq][ar][0]);
    gld16(gAh + k0 + 32, &Ah[aq + 4][ar][0]);
    if (APREC == 2){
      gld16(gAl + k0,      &Al[aq][ar][0]);
      gld16(gAl + k0 + 32, &Al[aq + 4][ar][0]);
    }
    gld16(gBh + k0,      &Bh[bq][br][0]);
    gld16(gBh + k0 + 32, &Bh[bq + 4][br][0]);
    if (BPREC == 2){
      gld16(gBl + k0,      &Bl[bq][br][0]);
      gld16(gBl + k0 + 32, &Bl[bq + 4][br][0]);
    }
    asm volatile("s_waitcnt vmcnt(0)" ::: "memory");
    __syncthreads();
    #pragma unroll
    for (int kh = 0; kh < 2; kh++){
      const int q = kh * 4 + quad;
      short8 ahf[2], alf[2], bhf[NF], blf[NF];
      #pragma unroll
      for (int i = 0; i < 2; i++){
        ahf[i] = *(const short8*)(&Ah[q][wm + i * 16 + l15][0]);
        if (APREC == 2) alf[i] = *(const short8*)(&Al[q][wm + i * 16 + l15][0]);
      }
      #pragma unroll
      for (int i = 0; i < NF; i++){
        bhf[i] = *(const short8*)(&Bh[q][wn + i * 16 + l15][0]);
        if (BPREC == 2) blf[i] = *(const short8*)(&Bl[q][wn + i * 16 + l15][0]);
      }
      #pragma unroll
      for (int mi = 0; mi < 2; mi++)
      #pragma unroll
      for (int ni = 0; ni < NF; ni++){
        if (APREC == 2)
          acc[mi][ni] = __builtin_amdgcn_mfma_f32_16x16x32_bf16(alf[mi], bhf[ni], acc[mi][ni], 0, 0, 0);
        if (BPREC == 2)
          acc[mi][ni] = __builtin_amdgcn_mfma_f32_16x16x32_bf16(ahf[mi], blf[ni], acc[mi][ni], 0, 0, 0);
        acc[mi][ni] = __builtin_amdgcn_mfma_f32_16x16x32_bf16(ahf[mi], bhf[ni], acc[mi][ni], 0, 0, 0);
      }
    }
  }
  #pragma unroll
  for (int mi = 0; mi < 2; mi++)
  #pragma unroll
  for (int ni = 0; ni < NF; ni++){
    int col = n0 + wn + ni * 16 + l15;
    float bval = bias ? bias[col] : 0.f;
    int rowb = m0 + wm + mi * 16 + quad * 4;
    #pragma unroll
    for (int rg = 0; rg < 4; rg++){
      float v = acc[mi][ni][rg] + bval;
      int row = rowb + rg;
      if (EPI == 0){
        ((float*)C0)[(size_t)row * N + col] = v;
      } else {
        float t = v + 0.044715f * v * v * v;
        float g = 0.5f * v * (1.f + tanhf(0.7978845608f * t));
        ((u16*)C0)[(size_t)row * N + col] = f2bf(g);
      }
    }
  }
}

// ---------------------------------------------------------------------------
// Dedicated W1 GEMM: 128x128 tile, BK=64, A bf16 plane, B hi plane (1-pass),
// gelu -> bf16. Proven clean (r10).
// ---------------------------------------------------------------------------
__global__ __launch_bounds__(256) void gemm128_k(const u16* __restrict__ Agh,
                                                 const u16* __restrict__ Bgh,
                                                 const float* __restrict__ bias,
                                                 u16* __restrict__ C0,
                                                 int M, int N, int K){
  __shared__ __align__(16) u16 Ah[8][128][8];
  __shared__ __align__(16) u16 Bh[8][128][8];
  const int m0 = blockIdx.x << 7, n0 = blockIdx.y << 7;
  const int tid = threadIdx.x;
  const int lane = tid & 63, wave = tid >> 6;
  const int quad = lane >> 4, l15 = lane & 15;
  const int wm = (wave >> 1) << 6, wn = (wave & 1) << 6;
  const int ar = tid & 127, q0 = tid >> 7;
  const u16* gA  = Agh + (size_t)(m0 + ar) * K + q0 * 8;
  const u16* gBhp = Bgh + (size_t)(n0 + ar) * K + q0 * 8;
  f4 acc[4][4] = {};
  for (int k0 = 0; k0 < K; k0 += 64){
    __syncthreads();
    #pragma unroll
    for (int j = 0; j < 4; j++){
      gld16(gA   + k0 + j * 16, &Ah[q0 + 2 * j][ar][0]);
      gld16(gBhp + k0 + j * 16, &Bh[q0 + 2 * j][ar][0]);
    }
    asm volatile("s_waitcnt vmcnt(0)" ::: "memory");
    __syncthreads();
    #pragma unroll
    for (int kh = 0; kh < 2; kh++){
      const int q = kh * 4 + quad;
      short8 af[4], bh8[4];
      #pragma unroll
      for (int i = 0; i < 4; i++){
        af[i]  = *(const short8*)(&Ah[q][wm + i * 16 + l15][0]);
        bh8[i] = *(const short8*)(&Bh[q][wn + i * 16 + l15][0]);
      }
      #pragma unroll
      for (int mi = 0; mi < 4; mi++)
      #pragma unroll
      for (int ni = 0; ni < 4; ni++)
        acc[mi][ni] = __builtin_amdgcn_mfma_f32_16x16x32_bf16(af[mi], bh8[ni], acc[mi][ni], 0, 0, 0);
    }
  }
  #pragma unroll
  for (int mi = 0; mi < 4; mi++)
  #pragma unroll
  for (int ni = 0; ni < 4; ni++){
    int col = n0 + wn + ni * 16 + l15;
    float bval = bias[col];
    int rowb = m0 + wm + mi * 16 + quad * 4;
    #pragma unroll
    for (int rg = 0; rg < 4; rg++){
      float v = acc[mi][ni][rg] + bval;
      float t = v + 0.044715f * v * v * v;
      float g = 0.5f * v * (1.f + tanhf(0.7978845608f * t));
      C0[(size_t)(rowb + rg) * N + col] = f2bf(g);
    }
  }
}

// ---------------------------------------------------------------------------
// Attention — r13 champion: online softmax, one wave per token; lane owns
// dims [4*lane,4*lane+4). EKV packed bf16: one 16B load per corner = k4|v4.
// ---------------------------------------------------------------------------
__device__ __forceinline__ void unpack8(int4 p, f4& k4, f4& v4){
  k4.x = bf2f((u16)(p.x & 0xffff)); k4.y = bf2f((u16)((unsigned)p.x >> 16));
  k4.z = bf2f((u16)(p.y & 0xffff)); k4.w = bf2f((u16)((unsigned)p.y >> 16));
  v4.x = bf2f((u16)(p.z & 0xffff)); v4.y = bf2f((u16)((unsigned)p.z >> 16));
  v4.z = bf2f((u16)(p.w & 0xffff)); v4.w = bf2f((u16)((unsigned)p.w >> 16));
}

__global__ __launch_bounds__(256) void attn_k(const float* __restrict__ q,
                                              const u16* __restrict__ EKV,
                                              const float* __restrict__ offb,
                                              const float* __restrict__ locb,
                                              const float* __restrict__ kvc,
                                              u16* __restrict__ ah){
  const int tid = threadIdx.x;
  const int wave = tid >> 6, lane = tid & 63;
  const int tok = blockIdx.x * 4 + wave;
  const int base = (tok >> 12) << 12;   // n*4096
  const int4* E = (const int4*)EKV;     // 16B per (row,lane)
  const f4* kvc4 = (const f4*)kvc;
  f4 qv  = *((const f4*)q + (size_t)tok * 64 + lane);
  f4 wk0 = kvc4[lane], wk1 = kvc4[64 + lane], bkv = kvc4[128 + lane];
  f4 wv0 = kvc4[192 + lane], wv1 = kvc4[256 + lane], bvv = kvc4[320 + lane];
  float m = -1e30f, l = 0.f;
  f4 acc = {0.f, 0.f, 0.f, 0.f};
  #pragma unroll
  for (int s = 0; s < 16; s++){
    float y = locb[tok * 32 + s * 2], x = locb[tok * 32 + s * 2 + 1];
    float o0 = offb[tok * 32 + s * 2], o1 = offb[tok * 32 + s * 2 + 1];
    float yf = floorf(y), xf = floorf(x);
    int y0 = (int)yf, x0 = (int)xf;
    int y1 = min(y0 + 1, 63), x1 = min(x0 + 1, 63);
    float wy = y - yf, wx = x - xf;
    int4 p00 = E[(size_t)(base + y0 * 64 + x0) * 64 + lane];
    int4 p01 = E[(size_t)(base + y0 * 64 + x1) * 64 + lane];
    int4 p10 = E[(size_t)(base + y1 * 64 + x0) * 64 + lane];
    int4 p11 = E[(size_t)(base + y1 * 64 + x1) * 64 + lane];
    f4 k00, v00, k01, v01, k10, v10, k11, v11;
    unpack8(p00, k00, v00); unpack8(p01, k01, v01);
    unpack8(p10, k10, v10); unpack8(p11, k11, v11);
    float w00 = (1.f - wy) * (1.f - wx), w01 = (1.f - wy) * wx;
    float w10 = wy * (1.f - wx), w11 = wy * wx;
    f4 kk = w00 * k00 + w01 * k01 + w10 * k10 + w11 * k11;
    f4 vv = w00 * v00 + w01 * v01 + w10 * v10 + w11 * v11;
    kk += o0 * wk0 + o1 * wk1 + bkv;
    vv += o0 * wv0 + o1 * wv1 + bvv;
    float p = qv.x * kk.x + qv.y * kk.y + qv.z * kk.z + qv.w * kk.w;
    p += __shfl_xor(p, 1); p += __shfl_xor(p, 2);
    p += __shfl_xor(p, 4); p += __shfl_xor(p, 8);
    p *= 0.125f;   // /sqrt(64)
    float mn = fmaxf(m, p);
    float cor = __expf(m - mn);
    float wgt = __expf(p - mn);
    l = l * cor + wgt;
    acc = acc * cor + wgt * vv;
    m = mn;
  }
  float inv = 1.f / l;
  f4 o = acc * inv;
  ushort4 h;
  h.x = f2bf(o.x); h.y = f2bf(o.y); h.z = f2bf(o.z); h.w = f2bf(o.w);
  *(ushort4*)(ah + (size_t)tok * 256 + lane * 4) = h;
}

// ---------------------------------------------------------------------------
// LayerNorm(a + b) * scale + bias. One wave per token.
// INP: 0 -> a0 fp32; 1 -> a0/a1 hi/lo planes.  OUTP: 0 -> fp32; 1 -> planes.
// ---------------------------------------------------------------------------
template<int INP, int OUTP>
__global__ __launch_bounds__(256) void ln_k(const void* __restrict__ a0,
                                            const void* __restrict__ a1,
                                            const float* __restrict__ b,
                                            const float* __restrict__ sc,
                                            const float* __restrict__ bi,
                                            void* __restrict__ o0,
                                            void* __restrict__ o1){
  const int tid = threadIdx.x;
  const int wave = tid >> 6, lane = tid & 63;
  const int tok = blockIdx.x * 4 + wave;
  float x0, x1, x2, x3;
  if (INP){
    ushort4 h = ((const ushort4*)a0)[(size_t)tok * 64 + lane];
    ushort4 lo = ((const ushort4*)a1)[(size_t)tok * 64 + lane];
    x0 = bf2f(h.x) + bf2f(lo.x); x1 = bf2f(h.y) + bf2f(lo.y);
    x2 = bf2f(h.z) + bf2f(lo.z); x3 = bf2f(h.w) + bf2f(lo.w);
  } else {
    f4 av = ((const f4*)a0)[(size_t)tok * 64 + lane];
    x0 = av.x; x1 = av.y; x2 = av.z; x3 = av.w;
  }
  f4 bv = ((const f4*)b)[(size_t)tok * 64 + lane];
  x0 += bv.x; x1 += bv.y; x2 += bv.z; x3 += bv.w;
  float sm = x0 + x1 + x2 + x3;
  float sq = x0 * x0 + x1 * x1 + x2 * x2 + x3 * x3;
  #pragma unroll
  for (int mm = 1; mm < 64; mm <<= 1){ sm += __shfl_xor(sm, mm); sq += __shfl_xor(sq, mm); }
  float mean = sm * (1.f / 256.f);
  float var = sq * (1.f / 256.f) - mean * mean;
  float rs = rsqrtf(var + 1e-6f);
  f4 sv = ((const f4*)sc)[lane];
  f4 bb = ((const f4*)bi)[lane];
  float y0 = (x0 - mean) * rs * sv.x + bb.x;
  float y1 = (x1 - mean) * rs * sv.y + bb.y;
  float y2 = (x2 - mean) * rs * sv.z + bb.z;
  float y3 = (x3 - mean) * rs * sv.w + bb.w;
  if (OUTP){
    ushort4 h, lo;
    h.x = f2bf(y0); lo.x = f2bf(y0 - bf2f(h.x));
    h.y = f2bf(y1); lo.y = f2bf(y1 - bf2f(h.y));
    h.z = f2bf(y2); lo.z = f2bf(y2 - bf2f(h.z));
    h.w = f2bf(y3); lo.w = f2bf(y3 - bf2f(h.w));
    ((ushort4*)o0)[(size_t)tok * 64 + lane] = h;
    ((ushort4*)o1)[(size_t)tok * 64 + lane] = lo;
  } else {
    f4 ov = {y0, y1, y2, y3};
    ((f4*)o0)[(size_t)tok * 64 + lane] = ov;
  }
}

// ---------------------------------------------------------------------------
extern "C" void kernel_launch(void* const* d_in, const int* in_sizes, int n_in,
                              void* d_out, int out_size, void* d_ws, size_t ws_size,
                              hipStream_t stream){
  const float* hs   = (const float*)d_in[0];
  const float* emb  = (const float*)d_in[1];
  const float* Woff = (const float*)d_in[2];
  const float* boff = (const float*)d_in[3];
  const float* Wkvp = (const float*)d_in[4];
  const float* bkvp = (const float*)d_in[5];
  const float* Wq   = (const float*)d_in[6];
  const float* bq   = (const float*)d_in[7];
  const float* Wk   = (const float*)d_in[8];
  const float* bk   = (const float*)d_in[9];
  const float* Wv   = (const float*)d_in[10];
  const float* bv   = (const float*)d_in[11];
  const float* Wo   = (const float*)d_in[12];
  const float* bo   = (const float*)d_in[13];
  const float* ln1s = (const float*)d_in[14];
  const float* ln1b = (const float*)d_in[15];
  const float* ln2s = (const float*)d_in[16];
  const float* ln2b = (const float*)d_in[17];
  const float* W1   = (const float*)d_in[18];
  const float* b1   = (const float*)d_in[19];
  const float* W2   = (const float*)d_in[20];
  const float* b2   = (const float*)d_in[21];

  char* w = (char*)d_ws;
  auto alloc = [&](size_t bytes){ char* p = w; w += (bytes + 255) & ~(size_t)255; return p; };
  // weight planes: [WqT | WkT | WvT | WoT] contiguous hi and lo
  u16* qkvoTh = (u16*)alloc(4 * 65536 * 2);
  u16* qkvoTl = (u16*)alloc(4 * 65536 * 2);
  u16* WqTh = qkvoTh;              u16* WqTl = qkvoTl;
  u16* kvWh = qkvoTh + 65536;      u16* kvWl = qkvoTl + 65536;   // [512,256]
  u16* WoTh = qkvoTh + 3 * 65536;
  u16* W1Th = (u16*)alloc(262144 * 2); u16* W1Tl = (u16*)alloc(262144 * 2);
  u16* W2Th = (u16*)alloc(262144 * 2); u16* W2Tl = (u16*)alloc(262144 * 2);
  float* kvc = (float*)alloc(1536 * 4);
  // slot1 (8.4 MB): hs hi/lo planes / attn hi plane / xb planes
  char* slot1 = alloc((size_t)NT * 256 * 4);
  u16* hsph = (u16*)slot1;          u16* hspl = hsph + (size_t)NT * 256;
  u16* attnh = hsph;
  u16* xbh = hsph;                  u16* xbl = hspl;
  // slot2 (8.4 MB): emb bf16 plane / aout fp32
  char* slot2 = alloc((size_t)NT * 256 * 4);
  u16* embh = (u16*)slot2;
  float* aout = (float*)slot2;
  // slot3 (8.4 MB): off+loc / mout fp32
  char* slot3 = alloc((size_t)NT * 256 * 4);
  float* off = (float*)slot3;       float* loc = off + (size_t)NT * 32;
  float* mout = (float*)slot3;
  // slot4 (16.8 MB): qb fp32 + EKV bf16 / h1 bf16 [NT,1024] (16 MB)
  char* slot4 = alloc((size_t)NT * 256 * 8);
  float* qb = (float*)slot4;
  u16* EKV = (u16*)(slot4 + (size_t)NT * 256 * 4);   // [NT,512] packed bf16
  u16* h1 = (u16*)slot4;                             // [NT,1024] bf16 plane
  if ((size_t)(w - (char*)d_ws) > ws_size) return;

  // ALL prep in one dispatch
  prepall_k<<<1794, 256, 0, stream>>>(hs, emb, Woff, boff, Wq, Wk, Wv, Wo, W1, W2,
                                      Wkvp, bkvp, bk, bv,
                                      hsph, hspl, embh, off, loc,
                                      qkvoTh, qkvoTl, W1Th, W1Tl, W2Th, W2Tl, kvc);

  // grouped q (3-pass) + EKV (2-pass), r13 per-BK staging
  qekv_k<<<1536, 256, 0, stream>>>(hsph, hspl, WqTh, WqTl, bq,
                                   embh, kvWh, kvWl, qb, EKV);

  // gather + online-softmax attention
  attn_k<<<2048, 256, 0, stream>>>(qb, EKV, off, loc, kvc, attnh);

  // out-proj (1-pass), LN1, MLP, LN2
  gemm_k<64, 1, 1, 0><<<dim3(128, 4), 256, 0, stream>>>(attnh, nullptr, WoTh, nullptr, bo, aout, NT, 256, 256);
  ln_k<0, 1><<<2048, 256, 0, stream>>>(hs, nullptr, aout, ln1s, ln1b, xbh, xbl);
  gemm128_k<<<dim3(64, 8), 256, 0, stream>>>(xbh, W1Th, b1, h1, NT, 1024, 256);
  gemm_k<64, 1, 1, 0><<<dim3(128, 4), 256, 0, stream>>>(h1, nullptr, W2Th, nullptr, b2, mout, NT, 256, 1024);
  ln_k<1, 0><<<2048, 256, 0, stream>>>(xbh, xbl, mout, ln2s, ln2b, d_out, nullptr);
}